// Round 5
// baseline (1400.819 us; speedup 1.0000x reference)
//
#include <hip/hip_runtime.h>

// ---------------------------------------------------------------------------
// TreeCaps forward, MI355X fp32. 3 persistent kernels + manual grid barriers.
// Fixed forest: node p's children are 4p+1..4p+4; nodes 0..255 internal.
// R1: wide VTS blocks. R2: dsweep 1 block/node. R3: cooperative fusion FAILED
//   (launches rejected: 71.7KB static LDS + 400-block cooperative grid).
// R4: same fusion, plain launches + monotonic atomic grid barrier (AGENT
//   scope), all kernels <= 40KB LDS, grids sized for guaranteed residency.
// ---------------------------------------------------------------------------

#define BG      32
#define NPG     1024
#define NLAY    4
#define INT_PG  256
#define M_INT   8192      // BG*INT_PG
#define NN      32768     // BG*NPG
#define EPG     1023
#define NS      50

// monotonic grid barrier: each block's thread 0 adds 1, spins until count
// reaches `target` (= barrier_index * num_blocks). AGENT-scope atomics give
// device-wide release/acquire (cross-XCD safe).
__device__ __forceinline__ void gbar(unsigned int* bar, unsigned int target) {
  __syncthreads();
  if (threadIdx.x == 0) {
    __threadfence();
    __hip_atomic_fetch_add(bar, 1u, __ATOMIC_ACQ_REL, __HIP_MEMORY_SCOPE_AGENT);
    while (__hip_atomic_load(bar, __ATOMIC_ACQUIRE, __HIP_MEMORY_SCOPE_AGENT) < target)
      __builtin_amdgcn_s_sleep(1);
  }
  __syncthreads();
}

// ======================= mega kernel (256 x 256) ===========================
// embed + 4x(fused gather+conv) + l2 + topk + buildU. LDS <= 20.5 KB.
__global__ __launch_bounds__(256) void k_mega(
    const int* __restrict__ tids, const int* __restrict__ kids,
    const float* __restrict__ temb, const float* __restrict__ kemb,
    const float* __restrict__ lw, const float* __restrict__ rw,
    const float* __restrict__ Wl, const float* __restrict__ Wr,
    const float* __restrict__ Wt, const float* __restrict__ bconv,
    float* __restrict__ h, float* __restrict__ feat,
    float* __restrict__ l2b, int* __restrict__ sel,
    float* __restrict__ U, float* __restrict__ Vsum,
    unsigned int* __restrict__ bar) {
  __shared__ union {
    struct { float Ws[32][128]; float AsT[32][36]; } c;                 // 20.5 KB
    struct { unsigned long long keys[1024]; unsigned long long red[256]; } t; // 10 KB
  } sm;
  int tid = threadIdx.x, bid = blockIdx.x;
  int gtid = bid * 256 + tid;
  unsigned int bt = 0;

  // ---- phase E: embedding h0 = concat(type_emb, token_emb) ----
  for (int i = gtid; i < NN * 32; i += 65536) {
    int n = i >> 5, c4 = i & 31;
    float4 v;
    if (c4 < 16) v = *(const float4*)(temb + tids[n] * 64 + c4 * 4);
    else         v = *(const float4*)(kemb + kids[n] * 64 + (c4 - 16) * 4);
    *(float4*)(h + n * 128 + c4 * 4) = v;
  }
  bt += 256; gbar(bar, bt);

  // ---- phase C: 4 conv layers ----
  int rowBase = bid * 32;
  int g = rowBase >> 8, pb = rowBase & 255;
  int nodeBase = g * 1024 + pb;
  int tx = tid & 31, ty = tid >> 5;
  int p8 = tid >> 3, c16 = (tid & 7) * 16;

  for (int l = 0; l < NLAY; ++l) {
    // prologue: gather weighted child sums + own row into REGISTERS
    float av[16], bv[16], cv[16];
    {
      int PL = pb + p8;
      const float* hp = h + (g * 1024 + PL) * 128 + c16;
      #pragma unroll
      for (int q = 0; q < 4; ++q) {
        float4 t4 = *(const float4*)(hp + q * 4);
        cv[q*4] = t4.x; cv[q*4+1] = t4.y; cv[q*4+2] = t4.z; cv[q*4+3] = t4.w;
      }
      #pragma unroll
      for (int i = 0; i < 16; ++i) { av[i] = 0.f; bv[i] = 0.f; }
      for (int j = 0; j < 4; ++j) {
        int cc = 4 * PL + 1 + j;
        if (cc < 1024) {
          int e = g * EPG + cc - 1;
          float lv = lw[e], rv = rw[e];
          const float* hc = h + (g * 1024 + cc) * 128 + c16;
          #pragma unroll
          for (int q = 0; q < 4; ++q) {
            float4 t4 = *(const float4*)(hc + q * 4);
            av[q*4]   = fmaf(lv, t4.x, av[q*4]);   bv[q*4]   = fmaf(rv, t4.x, bv[q*4]);
            av[q*4+1] = fmaf(lv, t4.y, av[q*4+1]); bv[q*4+1] = fmaf(rv, t4.y, bv[q*4+1]);
            av[q*4+2] = fmaf(lv, t4.z, av[q*4+2]); bv[q*4+2] = fmaf(rv, t4.z, bv[q*4+2]);
            av[q*4+3] = fmaf(lv, t4.w, av[q*4+3]); bv[q*4+3] = fmaf(rv, t4.w, bv[q*4+3]);
          }
        }
      }
    }
    bt += 256; gbar(bar, bt);   // all h reads done before epilogue h writes

    const float* WlL = Wl + l * 16384;
    const float* WrL = Wr + l * 16384;
    const float* WtL = Wt + l * 16384;
    float acc[4][4] = {};
    for (int kc = 0; kc < 12; ++kc) {
      int ssel = kc >> 2, koff = (kc & 3) * 32;
      const float* wsrc = ((ssel == 0) ? WlL : (ssel == 1) ? WrL : WtL) + koff * 128;
      float4 wv0, wv1, wv2, wv3;
      {
        int f0 = tid, f1 = tid + 256, f2 = tid + 512, f3 = tid + 768;
        wv0 = *(const float4*)(wsrc + (f0 >> 5) * 128 + (f0 & 31) * 4);
        wv1 = *(const float4*)(wsrc + (f1 >> 5) * 128 + (f1 & 31) * 4);
        wv2 = *(const float4*)(wsrc + (f2 >> 5) * 128 + (f2 & 31) * 4);
        wv3 = *(const float4*)(wsrc + (f3 >> 5) * 128 + (f3 & 31) * 4);
      }
      __syncthreads();                       // previous chunk's readers done
      {
        int f0 = tid, f1 = tid + 256, f2 = tid + 512, f3 = tid + 768;
        *(float4*)&sm.c.Ws[f0 >> 5][(f0 & 31) * 4] = wv0;
        *(float4*)&sm.c.Ws[f1 >> 5][(f1 & 31) * 4] = wv1;
        *(float4*)&sm.c.Ws[f2 >> 5][(f2 & 31) * 4] = wv2;
        *(float4*)&sm.c.Ws[f3 >> 5][(f3 & 31) * 4] = wv3;
      }
      // owning threads stream their register fragment into this chunk's AsT
      int rel = (tid & 7) - ((kc & 3) << 1);
      if (rel == 0 || rel == 1) {
        int kk0 = rel << 4;
        if (ssel == 0) {
          #pragma unroll
          for (int i = 0; i < 16; ++i) sm.c.AsT[kk0 + i][p8] = av[i];
        } else if (ssel == 1) {
          #pragma unroll
          for (int i = 0; i < 16; ++i) sm.c.AsT[kk0 + i][p8] = bv[i];
        } else {
          #pragma unroll
          for (int i = 0; i < 16; ++i) sm.c.AsT[kk0 + i][p8] = cv[i];
        }
      }
      __syncthreads();
      #pragma unroll
      for (int kk = 0; kk < 32; ++kk) {
        float4 wv = *(float4*)&sm.c.Ws[kk][tx * 4];
        float4 av2 = *(float4*)&sm.c.AsT[kk][ty * 4];
        float aa[4] = {av2.x, av2.y, av2.z, av2.w};
        float ww[4] = {wv.x, wv.y, wv.z, wv.w};
        #pragma unroll
        for (int i = 0; i < 4; ++i)
          #pragma unroll
          for (int j = 0; j < 4; ++j)
            acc[i][j] = fmaf(aa[i], ww[j], acc[i][j]);
      }
    }
    float4 bv4 = *(const float4*)(bconv + l * 128 + tx * 4);
    float bb[4] = {bv4.x, bv4.y, bv4.z, bv4.w};
    float* featL = feat + l * (M_INT * 128);
    #pragma unroll
    for (int i = 0; i < 4; ++i) {
      int r = ty * 4 + i;
      float4 o = make_float4(fmaxf(acc[i][0] + bb[0], 0.f),
                             fmaxf(acc[i][1] + bb[1], 0.f),
                             fmaxf(acc[i][2] + bb[2], 0.f),
                             fmaxf(acc[i][3] + bb[3], 0.f));
      *(float4*)(featL + (rowBase + r) * 128 + tx * 4) = o;
      *(float4*)(h + (nodeBase + r) * 128 + tx * 4) = o;
    }
    bt += 256; gbar(bar, bt);   // layer boundary
  }

  // ---- phase L2 ----
  {
    int w = bid * 4 + (tid >> 6);
    int lane = tid & 63;
    for (int gg = 0; gg < 32; ++gg) {
      int nd = gg * 1024 + w;
      float s = 0.f;
      if (w >= INT_PG) {
        const float* p = h + nd * 128;
        float a = p[lane], b = p[lane + 64];
        s = (a * a + b * b) * 4.f;
      } else {
        int row = (gg * INT_PG + w) * 128;
        #pragma unroll
        for (int l = 0; l < 4; ++l) {
          const float* p = feat + l * (M_INT * 128) + row;
          float a = p[lane], b = p[lane + 64];
          s += a * a + b * b;
        }
      }
      #pragma unroll
      for (int off = 32; off; off >>= 1) s += __shfl_down(s, off);
      if (lane == 0) l2b[nd] = s;
    }
  }
  bt += 256; gbar(bar, bt);

  // ---- phase TOPK (blocks 0..31) ----
  if (bid < 32) {
    int gg = bid;
    for (int i = tid; i < 1024; i += 256) {
      unsigned vb = __float_as_uint(l2b[gg * 1024 + i]);
      sm.t.keys[i] = ((unsigned long long)vb << 32) | (unsigned)(~i);
    }
    __syncthreads();
    for (int r = 0; r < 8; ++r) {
      unsigned long long best = 0ULL;
      for (int i = tid; i < 1024; i += 256) {
        unsigned long long k = sm.t.keys[i];
        best = (k > best) ? k : best;
      }
      sm.t.red[tid] = best;
      __syncthreads();
      for (int st = 128; st; st >>= 1) {
        if (tid < st) {
          unsigned long long a = sm.t.red[tid], b = sm.t.red[tid + st];
          sm.t.red[tid] = (b > a) ? b : a;
        }
        __syncthreads();
      }
      if (tid == 0) {
        unsigned long long k = sm.t.red[0];
        int idx = (int)(~(unsigned)(k & 0xffffffffu));
        sel[gg * 8 + r] = idx;
        sm.t.keys[idx] = 0ULL;
      }
      __syncthreads();
    }
  }
  bt += 256; gbar(bar, bt);

  // ---- phase BUILDU ----
  if (gtid < 32768) {
    int gg = gtid >> 10, rank = (gtid >> 7) & 7, hh = gtid & 127;
    int local = sel[gg * 8 + rank];
    float4 v;
    if (local >= INT_PG) {
      float x = h[(gg * NPG + local) * 128 + hh];
      v = make_float4(x, x, x, x);
    } else {
      int row = (gg * INT_PG + local) * 128 + hh;
      v.x = feat[row];
      v.y = feat[M_INT * 128 + row];
      v.z = feat[2 * M_INT * 128 + row];
      v.w = feat[3 * M_INT * 128 + row];
    }
    int o = gg * 1024 + rank * 128 + hh;
    ((float4*)U)[o] = v;
    ((float4*)Vsum)[o] = v;
  }
}

// ======================= VTS kernel (256 x 1024) ===========================
__global__ __launch_bounds__(1024) void k_vts(
    const float* __restrict__ U, float* __restrict__ Vsum,
    float* __restrict__ mw, float* __restrict__ sw, float* __restrict__ SCT,
    unsigned int* __restrict__ bar) {
  __shared__ union {
    struct { float4 Vs[1024]; float2 red[1024]; } a;                  // 24 KB
    struct { float4 Us[1024]; float2 ms[1024]; float4 par[1024]; } b; // 40 KB
  } s;
  int g = blockIdx.x >> 3, blk = (blockIdx.x & 7) * 128;
  int tid = threadIdx.x, l = tid & 63, p = tid >> 6;
  unsigned int bt = 0;

  for (int it = 0; it < 3; ++it) {
    // ---- phase A ----
    s.a.Vs[tid] = ((const float4*)Vsum)[g * 1024 + tid];
    __syncthreads();
    float4 u0 = ((const float4*)U)[g * 1024 + blk + l];
    float4 u1 = ((const float4*)U)[g * 1024 + blk + 64 + l];
    int j0 = p * 64;
    float m0 = -3.4e38f, m1 = -3.4e38f;
    for (int j = j0; j < j0 + 64; ++j) {
      float4 v = s.a.Vs[j];
      float a0 = u0.x * v.x + u0.y * v.y + u0.z * v.z + u0.w * v.w;
      float a1 = u1.x * v.x + u1.y * v.y + u1.z * v.z + u1.w * v.w;
      m0 = fmaxf(m0, a0); m1 = fmaxf(m1, a1);
    }
    s.a.red[tid] = make_float2(m0, m1);
    __syncthreads();
    #pragma unroll
    for (int st = 512; st >= 64; st >>= 1) {
      if (tid < st) {
        float2 a = s.a.red[tid], b = s.a.red[tid + st];
        s.a.red[tid] = make_float2(fmaxf(a.x, b.x), fmaxf(a.y, b.y));
      }
      __syncthreads();
    }
    float2 mm = s.a.red[l];
    __syncthreads();
    float s0 = 0.f, s1 = 0.f;
    for (int j = j0; j < j0 + 64; ++j) {
      float4 v = s.a.Vs[j];
      float a0 = u0.x * v.x + u0.y * v.y + u0.z * v.z + u0.w * v.w;
      float a1 = u1.x * v.x + u1.y * v.y + u1.z * v.z + u1.w * v.w;
      s0 += __expf(a0 - mm.x);
      s1 += __expf(a1 - mm.y);
    }
    s.a.red[tid] = make_float2(s0, s1);
    __syncthreads();
    #pragma unroll
    for (int st = 512; st >= 64; st >>= 1) {
      if (tid < st) {
        float2 a = s.a.red[tid], b = s.a.red[tid + st];
        s.a.red[tid] = make_float2(a.x + b.x, a.y + b.y);
      }
      __syncthreads();
    }
    if (tid < 64) {
      float2 ss = s.a.red[tid];
      mw[g * 1024 + blk + tid] = mm.x;
      mw[g * 1024 + blk + 64 + tid] = mm.y;
      sw[g * 1024 + blk + tid] = ss.x;
      sw[g * 1024 + blk + 64 + tid] = ss.y;
    }
    bt += 256; gbar(bar, bt);

    // ---- phase B ----
    s.b.Us[tid] = ((const float4*)U)[g * 1024 + tid];
    s.b.ms[tid] = make_float2(mw[g * 1024 + tid], 1.0f / sw[g * 1024 + tid]);
    __syncthreads();
    float4 v0 = ((const float4*)Vsum)[g * 1024 + blk + l];
    float4 v1 = ((const float4*)Vsum)[g * 1024 + blk + 64 + l];
    float4 acc0 = make_float4(0.f, 0.f, 0.f, 0.f);
    float4 acc1 = make_float4(0.f, 0.f, 0.f, 0.f);
    int i0 = p * 64;
    for (int i = i0; i < i0 + 64; ++i) {
      float4 uu = s.b.Us[i];
      float2 st2 = s.b.ms[i];
      float a0 = uu.x * v0.x + uu.y * v0.y + uu.z * v0.z + uu.w * v0.w;
      float a1 = uu.x * v1.x + uu.y * v1.y + uu.z * v1.z + uu.w * v1.w;
      float w0 = __expf(a0 - st2.x) * st2.y;
      float w1 = __expf(a1 - st2.x) * st2.y;
      acc0.x = fmaf(w0, uu.x, acc0.x); acc0.y = fmaf(w0, uu.y, acc0.y);
      acc0.z = fmaf(w0, uu.z, acc0.z); acc0.w = fmaf(w0, uu.w, acc0.w);
      acc1.x = fmaf(w1, uu.x, acc1.x); acc1.y = fmaf(w1, uu.y, acc1.y);
      acc1.z = fmaf(w1, uu.z, acc1.z); acc1.w = fmaf(w1, uu.w, acc1.w);
    }
    s.b.par[tid] = acc0;
    __syncthreads();
    #pragma unroll
    for (int st = 512; st >= 64; st >>= 1) {
      if (tid < st) {
        float4 a = s.b.par[tid], b = s.b.par[tid + st];
        s.b.par[tid] = make_float4(a.x + b.x, a.y + b.y, a.z + b.z, a.w + b.w);
      }
      __syncthreads();
    }
    float4 o0 = make_float4(0.f, 0.f, 0.f, 0.f);
    if (tid < 64) o0 = s.b.par[tid];
    __syncthreads();
    s.b.par[tid] = acc1;
    __syncthreads();
    #pragma unroll
    for (int st = 512; st >= 64; st >>= 1) {
      if (tid < st) {
        float4 a = s.b.par[tid], b = s.b.par[tid + st];
        s.b.par[tid] = make_float4(a.x + b.x, a.y + b.y, a.z + b.z, a.w + b.w);
      }
      __syncthreads();
    }
    if (tid < 64) {
      float4 o1 = s.b.par[tid];
      int j0c = blk + tid, j1c = blk + 64 + tid;
      if (it == 2) {
        float sq0 = o0.x * o0.x + o0.y * o0.y + o0.z * o0.z + o0.w * o0.w;
        float f0 = (sq0 / (1.f + sq0)) / (sqrtf(sq0 + 1e-10f) + 1e-8f);
        ((float4*)SCT)[j0c * 32 + g] = make_float4(o0.x * f0, o0.y * f0, o0.z * f0, o0.w * f0);
        float sq1 = o1.x * o1.x + o1.y * o1.y + o1.z * o1.z + o1.w * o1.w;
        float f1 = (sq1 / (1.f + sq1)) / (sqrtf(sq1 + 1e-10f) + 1e-8f);
        ((float4*)SCT)[j1c * 32 + g] = make_float4(o1.x * f1, o1.y * f1, o1.z * f1, o1.w * f1);
      } else {
        float4 w0 = ((const float4*)Vsum)[g * 1024 + j0c];
        float4 w1 = ((const float4*)Vsum)[g * 1024 + j1c];
        ((float4*)Vsum)[g * 1024 + j0c] = make_float4(w0.x + o0.x, w0.y + o0.y,
                                                      w0.z + o0.z, w0.w + o0.w);
        ((float4*)Vsum)[g * 1024 + j1c] = make_float4(w1.x + o1.x, w1.y + o1.y,
                                                      w1.z + o1.z, w1.w + o1.w);
      }
    }
    if (it < 2) { bt += 256; gbar(bar, bt); }
  }
}

// ====================== routing kernel (400 x 256) =========================
__global__ __launch_bounds__(256) void k_route(
    const float* __restrict__ Wjm, float* __restrict__ WT,
    const float* __restrict__ SCT, float* __restrict__ gT,
    float* __restrict__ delta, float* __restrict__ accZ0,
    float* __restrict__ accZ1, float* __restrict__ zbuf,
    float* __restrict__ out, unsigned int* __restrict__ bar) {
  __shared__ float4 wl4[2048];     // 32 KB WT slice, persistent after init
  __shared__ float zl[512];
  int tid = threadIdx.x, bid = blockIdx.x;
  int gtid = bid * 256 + tid;
  unsigned int bt = 0;

  // ---- init: transpose Wjm -> WT; zero accZ buffers ----
  {
    float* wtr = (float*)wl4;
    for (int n = bid; n < 1024; n += 400) {
      for (int i = tid; i < 3200; i += 256) wtr[i] = Wjm[n * 3200 + i];
      __syncthreads();
      for (int i = tid; i < 3200; i += 256) {
        int s = i >> 6, cm = i & 63, cc = cm >> 2, m = cm & 3;
        WT[(s * 1024 + n) * 64 + cm] = wtr[(cc * NS + s) * 4 + m];
      }
      __syncthreads();
    }
  }
  if (gtid < 6400) {
    float4 z4 = make_float4(0.f, 0.f, 0.f, 0.f);
    ((float4*)accZ0)[gtid] = z4;
    ((float4*)accZ1)[gtid] = z4;
  }
  bt += 400; gbar(bar, bt);

  // ---- load my WT slice once ----
  int sb = bid >> 3, nb = bid & 7, n0 = nb * 128;
  for (int i = tid; i < 2048; i += 256)
    wl4[i] = ((const float4*)WT)[(sb * 1024 + n0) * 16 + i];
  __syncthreads();
  int b = tid & 31, ch = tid >> 5;

  for (int it = 0; it < 3; ++it) {
    float* accC = (it & 1) ? accZ1 : accZ0;
    float* accO = (it & 1) ? accZ0 : accZ1;
    // ---- Z phase ----
    {
      const float4* sct = (const float4*)SCT + n0 * 32 + b;
      const float* gp = gT + (sb * 1024 + n0) * 32 + b;
      float a0 = 0.f, a1 = 0.f;
      for (int nn = 0; nn < 128; ++nn) {
        float4 w0 = wl4[nn * 16 + ch];
        float4 w1 = wl4[nn * 16 + ch + 8];
        float4 s4 = sct[nn * 32];
        float gm = (it == 0) ? 0.02f : gp[nn * 32];
        float t0 = w0.x * s4.x + w0.y * s4.y + w0.z * s4.z + w0.w * s4.w;
        float t1 = w1.x * s4.x + w1.y * s4.y + w1.z * s4.z + w1.w * s4.w;
        a0 = fmaf(gm, t0, a0);
        a1 = fmaf(gm, t1, a1);
      }
      atomicAdd(accC + (b * NS + sb) * 16 + ch, a0);
      atomicAdd(accC + (b * NS + sb) * 16 + ch + 8, a1);
      if (gtid < 25600) accO[gtid] = 0.f;
    }
    bt += 400; gbar(bar, bt);
    // ---- squash phase ----
    if (gtid < 1600) {
      const float4* a4 = (const float4*)accC + gtid * 4;
      float4 u0 = a4[0], u1 = a4[1], u2 = a4[2], u3 = a4[3];
      float sq = u0.x*u0.x + u0.y*u0.y + u0.z*u0.z + u0.w*u0.w
               + u1.x*u1.x + u1.y*u1.y + u1.z*u1.z + u1.w*u1.w
               + u2.x*u2.x + u2.y*u2.y + u2.z*u2.z + u2.w*u2.w
               + u3.x*u3.x + u3.y*u3.y + u3.z*u3.z + u3.w*u3.w;
      float f = (sq / (1.f + sq)) / (sqrtf(sq + 1e-10f) + 1e-8f);
      if (it == 2) {
        float lg = sqrtf(sq * f * f + 1e-10f);
        out[gtid] = lg;
        out[gtid + 1600] = lg;
      } else {
        float4* z4 = (float4*)zbuf + gtid * 4;
        z4[0] = make_float4(u0.x * f, u0.y * f, u0.z * f, u0.w * f);
        z4[1] = make_float4(u1.x * f, u1.y * f, u1.z * f, u1.w * f);
        z4[2] = make_float4(u2.x * f, u2.y * f, u2.z * f, u2.w * f);
        z4[3] = make_float4(u3.x * f, u3.y * f, u3.z * f, u3.w * f);
      }
    }
    if (it == 2) break;            // uniform exit: no barrier after final write
    bt += 400; gbar(bar, bt);
    // ---- D phase ----
    for (int i = tid; i < 512; i += 256) {
      int c = i >> 5, bb = i & 31;
      zl[c * 32 + bb] = zbuf[bb * 800 + sb * 16 + c];
    }
    __syncthreads();
    for (int item = tid; item < 4096; item += 256) {
      int nn = item >> 5, bb = item & 31;
      float4 sc4 = ((const float4*)SCT)[(n0 + nn) * 32 + bb];
      float dd = 0.f;
      #pragma unroll
      for (int c = 0; c < 16; ++c) {
        float4 w = wl4[nn * 16 + c];
        float y = w.x * sc4.x + w.y * sc4.y + w.z * sc4.z + w.w * sc4.w;
        dd = fmaf(zl[c * 32 + bb], y, dd);
      }
      float* dp = delta + (sb * 1024 + n0 + nn) * 32 + bb;
      if (it == 0) *dp = dd; else *dp = *dp + dd;
    }
    bt += 400; gbar(bar, bt);
    // ---- gamma phase ----
    if (gtid < 32768) {
      const float* dp = delta + gtid;
      float m = -3.4e38f;
      for (int s = 0; s < NS; ++s) m = fmaxf(m, dp[s * 32768]);
      float sum = 0.f;
      for (int s = 0; s < NS; ++s) sum += __expf(dp[s * 32768] - m);
      float inv = 1.0f / sum;
      float* gq = gT + gtid;
      for (int s = 0; s < NS; ++s) gq[s * 32768] = __expf(dp[s * 32768] - m) * inv;
    }
    bt += 400; gbar(bar, bt);
  }
}

// ---------------------------------------------------------------------------
extern "C" void kernel_launch(void* const* d_in, const int* in_sizes, int n_in,
                              void* d_out, int out_size, void* d_ws, size_t ws_size,
                              hipStream_t stream) {
  const int*   type_ids  = (const int*)d_in[0];
  const int*   token_ids = (const int*)d_in[1];
  const float* lw        = (const float*)d_in[4];
  const float* rw        = (const float*)d_in[5];
  const float* temb      = (const float*)d_in[7];
  const float* kemb      = (const float*)d_in[8];
  const float* Wl        = (const float*)d_in[9];
  const float* Wr        = (const float*)d_in[10];
  const float* Wt        = (const float*)d_in[11];
  const float* bconv     = (const float*)d_in[12];
  const float* Wjm       = (const float*)d_in[13];
  float* out = (float*)d_out;
  char* wsb = (char*)d_ws;

  // workspace layout (regions reused across phases; peak ~35.5 MB)
  float* h     = (float*)(wsb + 0);          // 16.78 MB (dead after k_mega)
  float* WT    = (float*)(wsb + 0);          // 12.5  MB (k_route, overlays h)
  float* feat  = (float*)(wsb + 16777216);   // 16.78 MB (dead after k_mega)
  float* gT    = (float*)(wsb + 16777216);   // 6.55  MB (k_route, overlays feat)
  float* delta = (float*)(wsb + 23330816);   // 6.55  MB
  float* accZ0 = (float*)(wsb + 29884416);   // 102 KB
  float* zbuf  = (float*)(wsb + 29986816);   // 102 KB
  float* accZ1 = (float*)(wsb + 30089216);   // 102 KB
  float* l2b   = (float*)(wsb + 33554432);   // 128 KB
  int*   sel   = (int*)  (wsb + 33685504);   // 1 KB
  float* U     = (float*)(wsb + 33686528);   // 512 KB
  float* Vsum  = (float*)(wsb + 34210816);   // 512 KB
  float* mw    = (float*)(wsb + 34735104);   // 128 KB
  float* sw    = (float*)(wsb + 34866176);   // 128 KB
  float* SCT   = (float*)(wsb + 34997248);   // 512 KB
  unsigned int* bar0 = (unsigned int*)(wsb + 35521536);
  unsigned int* bar1 = (unsigned int*)(wsb + 35521536 + 64);
  unsigned int* bar2 = (unsigned int*)(wsb + 35521536 + 128);

  hipMemsetAsync(wsb + 35521536, 0, 192, stream);

  k_mega<<<256, 256, 0, stream>>>(type_ids, token_ids, temb, kemb, lw, rw,
                                  Wl, Wr, Wt, bconv, h, feat, l2b, sel,
                                  U, Vsum, bar0);
  k_vts<<<256, 1024, 0, stream>>>(U, Vsum, mw, sw, SCT, bar1);
  k_route<<<400, 256, 0, stream>>>(Wjm, WT, SCT, gT, delta, accZ0, accZ1,
                                   zbuf, out, bar2);
}

// Round 6
// 858.375 us; speedup vs baseline: 1.6319x; 1.6319x over previous
//
#include <hip/hip_runtime.h>

// ---------------------------------------------------------------------------
// TreeCaps forward, MI355X fp32. 3 persistent kernels + manual grid barriers.
// Fixed forest: node p's children are 4p+1..4p+4; nodes 0..255 internal.
// R4: fused kernels + atomic grid barrier -> correct but barrier spin storm
//     (750us k_route at 3% VALUBusy: acquire-polls every 64cyc from 400 blks).
// R5: relaxed polls + s_sleep(32) + single acquire fence; conv chains through
//     feat (no h rewrites, 1 barrier/layer); k_route loads Wjm directly
//     transposed to LDS (WT buffer + transpose pass + barrier eliminated).
// ---------------------------------------------------------------------------

#define BG      32
#define NPG     1024
#define NLAY    4
#define INT_PG  256
#define M_INT   8192      // BG*INT_PG
#define NN      32768     // BG*NPG
#define EPG     1023
#define NS      50

// monotonic grid barrier. Arrive: ACQ_REL fetch_add (release = L2 writeback).
// Poll: RELAXED agent-scope loads (no cache invalidate per poll), throttled
// by s_sleep(32) (~0.85us). One ACQUIRE fence after exit.
__device__ __forceinline__ void gbar(unsigned int* bar, unsigned int target) {
  __syncthreads();
  if (threadIdx.x == 0) {
    __hip_atomic_fetch_add(bar, 1u, __ATOMIC_ACQ_REL, __HIP_MEMORY_SCOPE_AGENT);
    while (__hip_atomic_load(bar, __ATOMIC_RELAXED, __HIP_MEMORY_SCOPE_AGENT) < target)
      __builtin_amdgcn_s_sleep(32);
    __builtin_amdgcn_fence(__ATOMIC_ACQUIRE, "agent");
  }
  __syncthreads();
}

// ======================= mega kernel (256 x 256) ===========================
// embed + 4x(fused gather+conv, feat-chained) + l2 + topk + buildU. 7 barriers.
__global__ __launch_bounds__(256) void k_mega(
    const int* __restrict__ tids, const int* __restrict__ kids,
    const float* __restrict__ temb, const float* __restrict__ kemb,
    const float* __restrict__ lw, const float* __restrict__ rw,
    const float* __restrict__ Wl, const float* __restrict__ Wr,
    const float* __restrict__ Wt, const float* __restrict__ bconv,
    float* __restrict__ h, float* __restrict__ feat,
    float* __restrict__ l2b, int* __restrict__ sel,
    float* __restrict__ U, float* __restrict__ Vsum,
    unsigned int* __restrict__ bar) {
  __shared__ union {
    struct { float Ws[32][128]; float AsT[32][36]; } c;                 // 20.5 KB
    struct { unsigned long long keys[1024]; unsigned long long red[256]; } t;
  } sm;
  int tid = threadIdx.x, bid = blockIdx.x;
  int gtid = bid * 256 + tid;
  unsigned int bt = 0;

  // ---- phase E: embedding h0 = concat(type_emb, token_emb); h is then
  //      immutable for the whole kernel ----
  for (int i = gtid; i < NN * 32; i += 65536) {
    int n = i >> 5, c4 = i & 31;
    float4 v;
    if (c4 < 16) v = *(const float4*)(temb + tids[n] * 64 + c4 * 4);
    else         v = *(const float4*)(kemb + kids[n] * 64 + (c4 - 16) * 4);
    *(float4*)(h + n * 128 + c4 * 4) = v;
  }
  bt += 256; gbar(bar, bt);

  // ---- phase C: 4 conv layers; layer l reads internal rows from feat[l-1],
  //      leaves from h; writes only feat[l]. One barrier per layer. ----
  int rowBase = bid * 32;
  int g = rowBase >> 8, pb = rowBase & 255;
  int tx = tid & 31, ty = tid >> 5;
  int p8 = tid >> 3, c16 = (tid & 7) * 16;

  for (int l = 0; l < NLAY; ++l) {
    const float* featPrev = feat + (l - 1) * (M_INT * 128);   // valid for l>0
    // prologue: gather weighted child sums + own row into registers
    float av[16], bv[16], cv[16];
    {
      int PL = pb + p8;
      const float* hp = (l == 0) ? (h + (g * 1024 + PL) * 128 + c16)
                                 : (featPrev + (g * 256 + PL) * 128 + c16);
      #pragma unroll
      for (int q = 0; q < 4; ++q) {
        float4 t4 = *(const float4*)(hp + q * 4);
        cv[q*4] = t4.x; cv[q*4+1] = t4.y; cv[q*4+2] = t4.z; cv[q*4+3] = t4.w;
      }
      #pragma unroll
      for (int i = 0; i < 16; ++i) { av[i] = 0.f; bv[i] = 0.f; }
      for (int j = 0; j < 4; ++j) {
        int cc = 4 * PL + 1 + j;
        if (cc < 1024) {
          int e = g * EPG + cc - 1;
          float lv = lw[e], rv = rw[e];
          const float* hc = (l > 0 && cc < 256)
                          ? (featPrev + (g * 256 + cc) * 128 + c16)
                          : (h + (g * 1024 + cc) * 128 + c16);
          #pragma unroll
          for (int q = 0; q < 4; ++q) {
            float4 t4 = *(const float4*)(hc + q * 4);
            av[q*4]   = fmaf(lv, t4.x, av[q*4]);   bv[q*4]   = fmaf(rv, t4.x, bv[q*4]);
            av[q*4+1] = fmaf(lv, t4.y, av[q*4+1]); bv[q*4+1] = fmaf(rv, t4.y, bv[q*4+1]);
            av[q*4+2] = fmaf(lv, t4.z, av[q*4+2]); bv[q*4+2] = fmaf(rv, t4.z, bv[q*4+2]);
            av[q*4+3] = fmaf(lv, t4.w, av[q*4+3]); bv[q*4+3] = fmaf(rv, t4.w, bv[q*4+3]);
          }
        }
      }
    }

    const float* WlL = Wl + l * 16384;
    const float* WrL = Wr + l * 16384;
    const float* WtL = Wt + l * 16384;
    float acc[4][4] = {};
    for (int kc = 0; kc < 12; ++kc) {
      int ssel = kc >> 2, koff = (kc & 3) * 32;
      const float* wsrc = ((ssel == 0) ? WlL : (ssel == 1) ? WrL : WtL) + koff * 128;
      float4 wv0, wv1, wv2, wv3;
      {
        int f0 = tid, f1 = tid + 256, f2 = tid + 512, f3 = tid + 768;
        wv0 = *(const float4*)(wsrc + (f0 >> 5) * 128 + (f0 & 31) * 4);
        wv1 = *(const float4*)(wsrc + (f1 >> 5) * 128 + (f1 & 31) * 4);
        wv2 = *(const float4*)(wsrc + (f2 >> 5) * 128 + (f2 & 31) * 4);
        wv3 = *(const float4*)(wsrc + (f3 >> 5) * 128 + (f3 & 31) * 4);
      }
      __syncthreads();                       // previous chunk's readers done
      {
        int f0 = tid, f1 = tid + 256, f2 = tid + 512, f3 = tid + 768;
        *(float4*)&sm.c.Ws[f0 >> 5][(f0 & 31) * 4] = wv0;
        *(float4*)&sm.c.Ws[f1 >> 5][(f1 & 31) * 4] = wv1;
        *(float4*)&sm.c.Ws[f2 >> 5][(f2 & 31) * 4] = wv2;
        *(float4*)&sm.c.Ws[f3 >> 5][(f3 & 31) * 4] = wv3;
      }
      // owning threads stream their register fragment into this chunk's AsT
      int rel = (tid & 7) - ((kc & 3) << 1);
      if (rel == 0 || rel == 1) {
        int kk0 = rel << 4;
        if (ssel == 0) {
          #pragma unroll
          for (int i = 0; i < 16; ++i) sm.c.AsT[kk0 + i][p8] = av[i];
        } else if (ssel == 1) {
          #pragma unroll
          for (int i = 0; i < 16; ++i) sm.c.AsT[kk0 + i][p8] = bv[i];
        } else {
          #pragma unroll
          for (int i = 0; i < 16; ++i) sm.c.AsT[kk0 + i][p8] = cv[i];
        }
      }
      __syncthreads();
      #pragma unroll
      for (int kk = 0; kk < 32; ++kk) {
        float4 wv = *(float4*)&sm.c.Ws[kk][tx * 4];
        float4 av2 = *(float4*)&sm.c.AsT[kk][ty * 4];
        float aa[4] = {av2.x, av2.y, av2.z, av2.w};
        float ww[4] = {wv.x, wv.y, wv.z, wv.w};
        #pragma unroll
        for (int i = 0; i < 4; ++i)
          #pragma unroll
          for (int j = 0; j < 4; ++j)
            acc[i][j] = fmaf(aa[i], ww[j], acc[i][j]);
      }
    }
    float4 bv4 = *(const float4*)(bconv + l * 128 + tx * 4);
    float bb[4] = {bv4.x, bv4.y, bv4.z, bv4.w};
    float* featL = feat + l * (M_INT * 128);
    #pragma unroll
    for (int i = 0; i < 4; ++i) {
      int r = ty * 4 + i;
      float4 o = make_float4(fmaxf(acc[i][0] + bb[0], 0.f),
                             fmaxf(acc[i][1] + bb[1], 0.f),
                             fmaxf(acc[i][2] + bb[2], 0.f),
                             fmaxf(acc[i][3] + bb[3], 0.f));
      *(float4*)(featL + (rowBase + r) * 128 + tx * 4) = o;
    }
    bt += 256; gbar(bar, bt);   // feat[l] visible to all
  }

  // ---- phase L2 ----
  {
    int w = bid * 4 + (tid >> 6);
    int lane = tid & 63;
    for (int gg = 0; gg < 32; ++gg) {
      int nd = gg * 1024 + w;
      float s = 0.f;
      if (w >= INT_PG) {
        const float* p = h + nd * 128;
        float a = p[lane], b = p[lane + 64];
        s = (a * a + b * b) * 4.f;
      } else {
        int row = (gg * INT_PG + w) * 128;
        #pragma unroll
        for (int l = 0; l < 4; ++l) {
          const float* p = feat + l * (M_INT * 128) + row;
          float a = p[lane], b = p[lane + 64];
          s += a * a + b * b;
        }
      }
      #pragma unroll
      for (int off = 32; off; off >>= 1) s += __shfl_down(s, off);
      if (lane == 0) l2b[nd] = s;
    }
  }
  bt += 256; gbar(bar, bt);

  // ---- phase TOPK (blocks 0..31), JAX tie-break: lower index first ----
  if (bid < 32) {
    int gg = bid;
    for (int i = tid; i < 1024; i += 256) {
      unsigned vb = __float_as_uint(l2b[gg * 1024 + i]);
      sm.t.keys[i] = ((unsigned long long)vb << 32) | (unsigned)(~i);
    }
    __syncthreads();
    for (int r = 0; r < 8; ++r) {
      unsigned long long best = 0ULL;
      for (int i = tid; i < 1024; i += 256) {
        unsigned long long k = sm.t.keys[i];
        best = (k > best) ? k : best;
      }
      sm.t.red[tid] = best;
      __syncthreads();
      for (int st = 128; st; st >>= 1) {
        if (tid < st) {
          unsigned long long a = sm.t.red[tid], b = sm.t.red[tid + st];
          sm.t.red[tid] = (b > a) ? b : a;
        }
        __syncthreads();
      }
      if (tid == 0) {
        unsigned long long k = sm.t.red[0];
        int idx = (int)(~(unsigned)(k & 0xffffffffu));
        sel[gg * 8 + r] = idx;
        sm.t.keys[idx] = 0ULL;
      }
      __syncthreads();
    }
  }
  bt += 256; gbar(bar, bt);

  // ---- phase BUILDU ----
  if (gtid < 32768) {
    int gg = gtid >> 10, rank = (gtid >> 7) & 7, hh = gtid & 127;
    int local = sel[gg * 8 + rank];
    float4 v;
    if (local >= INT_PG) {
      float x = h[(gg * NPG + local) * 128 + hh];
      v = make_float4(x, x, x, x);
    } else {
      int row = (gg * INT_PG + local) * 128 + hh;
      v.x = feat[row];
      v.y = feat[M_INT * 128 + row];
      v.z = feat[2 * M_INT * 128 + row];
      v.w = feat[3 * M_INT * 128 + row];
    }
    int o = gg * 1024 + rank * 128 + hh;
    ((float4*)U)[o] = v;
    ((float4*)Vsum)[o] = v;
  }
}

// ======================= VTS kernel (256 x 1024) ===========================
__global__ __launch_bounds__(1024) void k_vts(
    const float* __restrict__ U, float* __restrict__ Vsum,
    float* __restrict__ mw, float* __restrict__ sw, float* __restrict__ SCT,
    unsigned int* __restrict__ bar) {
  __shared__ union {
    struct { float4 Vs[1024]; float2 red[1024]; } a;                  // 24 KB
    struct { float4 Us[1024]; float2 ms[1024]; float4 par[1024]; } b; // 40 KB
  } s;
  int g = blockIdx.x >> 3, blk = (blockIdx.x & 7) * 128;
  int tid = threadIdx.x, l = tid & 63, p = tid >> 6;
  unsigned int bt = 0;

  for (int it = 0; it < 3; ++it) {
    // ---- phase A: row softmax stats of alpha = U @ Vsum.T ----
    s.a.Vs[tid] = ((const float4*)Vsum)[g * 1024 + tid];
    __syncthreads();
    float4 u0 = ((const float4*)U)[g * 1024 + blk + l];
    float4 u1 = ((const float4*)U)[g * 1024 + blk + 64 + l];
    int j0 = p * 64;
    float m0 = -3.4e38f, m1 = -3.4e38f;
    for (int j = j0; j < j0 + 64; ++j) {
      float4 v = s.a.Vs[j];
      float a0 = u0.x * v.x + u0.y * v.y + u0.z * v.z + u0.w * v.w;
      float a1 = u1.x * v.x + u1.y * v.y + u1.z * v.z + u1.w * v.w;
      m0 = fmaxf(m0, a0); m1 = fmaxf(m1, a1);
    }
    s.a.red[tid] = make_float2(m0, m1);
    __syncthreads();
    #pragma unroll
    for (int st = 512; st >= 64; st >>= 1) {
      if (tid < st) {
        float2 a = s.a.red[tid], b = s.a.red[tid + st];
        s.a.red[tid] = make_float2(fmaxf(a.x, b.x), fmaxf(a.y, b.y));
      }
      __syncthreads();
    }
    float2 mm = s.a.red[l];
    __syncthreads();
    float s0 = 0.f, s1 = 0.f;
    for (int j = j0; j < j0 + 64; ++j) {
      float4 v = s.a.Vs[j];
      float a0 = u0.x * v.x + u0.y * v.y + u0.z * v.z + u0.w * v.w;
      float a1 = u1.x * v.x + u1.y * v.y + u1.z * v.z + u1.w * v.w;
      s0 += __expf(a0 - mm.x);
      s1 += __expf(a1 - mm.y);
    }
    s.a.red[tid] = make_float2(s0, s1);
    __syncthreads();
    #pragma unroll
    for (int st = 512; st >= 64; st >>= 1) {
      if (tid < st) {
        float2 a = s.a.red[tid], b = s.a.red[tid + st];
        s.a.red[tid] = make_float2(a.x + b.x, a.y + b.y);
      }
      __syncthreads();
    }
    if (tid < 64) {
      float2 ss = s.a.red[tid];
      mw[g * 1024 + blk + tid] = mm.x;
      mw[g * 1024 + blk + 64 + tid] = mm.y;
      sw[g * 1024 + blk + tid] = ss.x;
      sw[g * 1024 + blk + 64 + tid] = ss.y;
    }
    bt += 256; gbar(bar, bt);

    // ---- phase B: Vnew = beta.T @ U ----
    s.b.Us[tid] = ((const float4*)U)[g * 1024 + tid];
    s.b.ms[tid] = make_float2(mw[g * 1024 + tid], 1.0f / sw[g * 1024 + tid]);
    __syncthreads();
    float4 v0 = ((const float4*)Vsum)[g * 1024 + blk + l];
    float4 v1 = ((const float4*)Vsum)[g * 1024 + blk + 64 + l];
    float4 acc0 = make_float4(0.f, 0.f, 0.f, 0.f);
    float4 acc1 = make_float4(0.f, 0.f, 0.f, 0.f);
    int i0 = p * 64;
    for (int i = i0; i < i0 + 64; ++i) {
      float4 uu = s.b.Us[i];
      float2 st2 = s.b.ms[i];
      float a0 = uu.x * v0.x + uu.y * v0.y + uu.z * v0.z + uu.w * v0.w;
      float a1 = uu.x * v1.x + uu.y * v1.y + uu.z * v1.z + uu.w * v1.w;
      float w0 = __expf(a0 - st2.x) * st2.y;
      float w1 = __expf(a1 - st2.x) * st2.y;
      acc0.x = fmaf(w0, uu.x, acc0.x); acc0.y = fmaf(w0, uu.y, acc0.y);
      acc0.z = fmaf(w0, uu.z, acc0.z); acc0.w = fmaf(w0, uu.w, acc0.w);
      acc1.x = fmaf(w1, uu.x, acc1.x); acc1.y = fmaf(w1, uu.y, acc1.y);
      acc1.z = fmaf(w1, uu.z, acc1.z); acc1.w = fmaf(w1, uu.w, acc1.w);
    }
    s.b.par[tid] = acc0;
    __syncthreads();
    #pragma unroll
    for (int st = 512; st >= 64; st >>= 1) {
      if (tid < st) {
        float4 a = s.b.par[tid], b = s.b.par[tid + st];
        s.b.par[tid] = make_float4(a.x + b.x, a.y + b.y, a.z + b.z, a.w + b.w);
      }
      __syncthreads();
    }
    float4 o0 = make_float4(0.f, 0.f, 0.f, 0.f);
    if (tid < 64) o0 = s.b.par[tid];
    __syncthreads();
    s.b.par[tid] = acc1;
    __syncthreads();
    #pragma unroll
    for (int st = 512; st >= 64; st >>= 1) {
      if (tid < st) {
        float4 a = s.b.par[tid], b = s.b.par[tid + st];
        s.b.par[tid] = make_float4(a.x + b.x, a.y + b.y, a.z + b.z, a.w + b.w);
      }
      __syncthreads();
    }
    if (tid < 64) {
      float4 o1 = s.b.par[tid];
      int j0c = blk + tid, j1c = blk + 64 + tid;
      if (it == 2) {
        float sq0 = o0.x * o0.x + o0.y * o0.y + o0.z * o0.z + o0.w * o0.w;
        float f0 = (sq0 / (1.f + sq0)) / (sqrtf(sq0 + 1e-10f) + 1e-8f);
        ((float4*)SCT)[j0c * 32 + g] = make_float4(o0.x * f0, o0.y * f0, o0.z * f0, o0.w * f0);
        float sq1 = o1.x * o1.x + o1.y * o1.y + o1.z * o1.z + o1.w * o1.w;
        float f1 = (sq1 / (1.f + sq1)) / (sqrtf(sq1 + 1e-10f) + 1e-8f);
        ((float4*)SCT)[j1c * 32 + g] = make_float4(o1.x * f1, o1.y * f1, o1.z * f1, o1.w * f1);
      } else {
        float4 w0 = ((const float4*)Vsum)[g * 1024 + j0c];
        float4 w1 = ((const float4*)Vsum)[g * 1024 + j1c];
        ((float4*)Vsum)[g * 1024 + j0c] = make_float4(w0.x + o0.x, w0.y + o0.y,
                                                      w0.z + o0.z, w0.w + o0.w);
        ((float4*)Vsum)[g * 1024 + j1c] = make_float4(w1.x + o1.x, w1.y + o1.y,
                                                      w1.z + o1.z, w1.w + o1.w);
      }
    }
    if (it < 2) { bt += 256; gbar(bar, bt); }
  }
}

// ====================== routing kernel (400 x 256) =========================
// Wjm slice loaded directly transposed into LDS (no WT buffer). 9 barriers.
__global__ __launch_bounds__(256) void k_route(
    const float* __restrict__ Wjm,
    const float* __restrict__ SCT, float* __restrict__ gT,
    float* __restrict__ delta, float* __restrict__ accZ0,
    float* __restrict__ accZ1, float* __restrict__ zbuf,
    float* __restrict__ out, unsigned int* __restrict__ bar) {
  __shared__ float4 wl4[2048];     // [nn][c] float4 over m — 32 KB
  __shared__ float zl[512];
  int tid = threadIdx.x, bid = blockIdx.x;
  int gtid = bid * 256 + tid;
  unsigned int bt = 0;

  // ---- load my Wjm slice transposed: wl4[nn*16+c] = Wjm[n0+nn][c][sb][:] ----
  int sb = bid >> 3, nb = bid & 7, n0 = nb * 128;
  for (int i = tid; i < 2048; i += 256) {
    int nn = i >> 4, c = i & 15;
    wl4[i] = *(const float4*)(Wjm + (n0 + nn) * 3200 + (c * 50 + sb) * 4);
  }
  __syncthreads();
  int b = tid & 31, ch = tid >> 5;

  for (int it = 0; it < 3; ++it) {
    float* accC = (it & 1) ? accZ1 : accZ0;   // zeroed by host memset (it=0,1)
    float* accO = (it & 1) ? accZ0 : accZ1;   // or by previous iter's re-zero
    // ---- Z phase: accZ[b][s][c] += sum_n gamma * v ----
    {
      const float4* sct = (const float4*)SCT + n0 * 32 + b;
      const float* gp = gT + (sb * 1024 + n0) * 32 + b;
      float a0 = 0.f, a1 = 0.f;
      for (int nn = 0; nn < 128; ++nn) {
        float4 w0 = wl4[nn * 16 + ch];
        float4 w1 = wl4[nn * 16 + ch + 8];
        float4 s4 = sct[nn * 32];
        float gm = (it == 0) ? 0.02f : gp[nn * 32];
        float t0 = w0.x * s4.x + w0.y * s4.y + w0.z * s4.z + w0.w * s4.w;
        float t1 = w1.x * s4.x + w1.y * s4.y + w1.z * s4.z + w1.w * s4.w;
        a0 = fmaf(gm, t0, a0);
        a1 = fmaf(gm, t1, a1);
      }
      atomicAdd(accC + (b * NS + sb) * 16 + ch, a0);
      atomicAdd(accC + (b * NS + sb) * 16 + ch + 8, a1);
      if (gtid < 25600) accO[gtid] = 0.f;     // re-zero consumed buffer
    }
    bt += 400; gbar(bar, bt);
    // ---- squash phase ----
    if (gtid < 1600) {
      const float4* a4 = (const float4*)accC + gtid * 4;
      float4 u0 = a4[0], u1 = a4[1], u2 = a4[2], u3 = a4[3];
      float sq = u0.x*u0.x + u0.y*u0.y + u0.z*u0.z + u0.w*u0.w
               + u1.x*u1.x + u1.y*u1.y + u1.z*u1.z + u1.w*u1.w
               + u2.x*u2.x + u2.y*u2.y + u2.z*u2.z + u2.w*u2.w
               + u3.x*u3.x + u3.y*u3.y + u3.z*u3.z + u3.w*u3.w;
      float f = (sq / (1.f + sq)) / (sqrtf(sq + 1e-10f) + 1e-8f);
      if (it == 2) {
        float lg = sqrtf(sq * f * f + 1e-10f);
        out[gtid] = lg;
        out[gtid + 1600] = lg;
      } else {
        float4* z4 = (float4*)zbuf + gtid * 4;
        z4[0] = make_float4(u0.x * f, u0.y * f, u0.z * f, u0.w * f);
        z4[1] = make_float4(u1.x * f, u1.y * f, u1.z * f, u1.w * f);
        z4[2] = make_float4(u2.x * f, u2.y * f, u2.z * f, u2.w * f);
        z4[3] = make_float4(u3.x * f, u3.y * f, u3.z * f, u3.w * f);
      }
    }
    if (it == 2) break;            // uniform exit
    bt += 400; gbar(bar, bt);
    // ---- D phase: delta[sb][n][b] (+)= sum_c v * z ----
    for (int i = tid; i < 512; i += 256) {
      int c = i >> 5, bb = i & 31;
      zl[c * 32 + bb] = zbuf[bb * 800 + sb * 16 + c];
    }
    __syncthreads();
    for (int item = tid; item < 4096; item += 256) {
      int nn = item >> 5, bb = item & 31;
      float4 sc4 = ((const float4*)SCT)[(n0 + nn) * 32 + bb];
      float dd = 0.f;
      #pragma unroll
      for (int c = 0; c < 16; ++c) {
        float4 w = wl4[nn * 16 + c];
        float y = w.x * sc4.x + w.y * sc4.y + w.z * sc4.z + w.w * sc4.w;
        dd = fmaf(zl[c * 32 + bb], y, dd);
      }
      float* dp = delta + (sb * 1024 + n0 + nn) * 32 + bb;
      if (it == 0) *dp = dd; else *dp = *dp + dd;
    }
    bt += 400; gbar(bar, bt);
    // ---- gamma phase: gT = softmax_s(delta) ----
    if (gtid < 32768) {
      const float* dp = delta + gtid;
      float m = -3.4e38f;
      for (int s2 = 0; s2 < NS; ++s2) m = fmaxf(m, dp[s2 * 32768]);
      float sum = 0.f;
      for (int s2 = 0; s2 < NS; ++s2) sum += __expf(dp[s2 * 32768] - m);
      float inv = 1.0f / sum;
      float* gq = gT + gtid;
      for (int s2 = 0; s2 < NS; ++s2) gq[s2 * 32768] = __expf(dp[s2 * 32768] - m) * inv;
    }
    bt += 400; gbar(bar, bt);
  }
}

// ---------------------------------------------------------------------------
extern "C" void kernel_launch(void* const* d_in, const int* in_sizes, int n_in,
                              void* d_out, int out_size, void* d_ws, size_t ws_size,
                              hipStream_t stream) {
  const int*   type_ids  = (const int*)d_in[0];
  const int*   token_ids = (const int*)d_in[1];
  const float* lw        = (const float*)d_in[4];
  const float* rw        = (const float*)d_in[5];
  const float* temb      = (const float*)d_in[7];
  const float* kemb      = (const float*)d_in[8];
  const float* Wl        = (const float*)d_in[9];
  const float* Wr        = (const float*)d_in[10];
  const float* Wt        = (const float*)d_in[11];
  const float* bconv     = (const float*)d_in[12];
  const float* Wjm       = (const float*)d_in[13];
  float* out = (float*)d_out;
  char* wsb = (char*)d_ws;

  // workspace layout (~35.8 MB peak; gT/delta overlay h which is dead in route)
  float* h     = (float*)(wsb + 0);          // 16.78 MB (k_mega)
  float* gT    = (float*)(wsb + 0);          // 6.55 MB  (k_route)
  float* delta = (float*)(wsb + 6553600);    // 6.55 MB  (k_route)
  float* feat  = (float*)(wsb + 16777216);   // 16.78 MB (k_mega; dead in route)
  float* l2b   = (float*)(wsb + 33554432);   // 128 KB
  int*   sel   = (int*)  (wsb + 33685504);   // 1 KB
  float* U     = (float*)(wsb + 33686528);   // 512 KB
  float* Vsum  = (float*)(wsb + 34210816);   // 512 KB
  float* mw    = (float*)(wsb + 34735104);   // 128 KB
  float* sw    = (float*)(wsb + 34866176);   // 128 KB
  float* SCT   = (float*)(wsb + 34997248);   // 512 KB
  float* accZ0 = (float*)(wsb + 35521536);   // 100 KB
  float* accZ1 = (float*)(wsb + 35623936);   // 100 KB
  float* zbuf  = (float*)(wsb + 35726336);   // 100 KB
  unsigned int* bar0 = (unsigned int*)(wsb + 35828736);
  unsigned int* bar1 = (unsigned int*)(wsb + 35828736 + 64);
  unsigned int* bar2 = (unsigned int*)(wsb + 35828736 + 128);

  // zero accZ0+accZ1 (+zbuf, harmless) and the 3 barrier counters in one shot
  hipMemsetAsync(wsb + 35521536, 0, 307392, stream);

  k_mega<<<256, 256, 0, stream>>>(type_ids, token_ids, temb, kemb, lw, rw,
                                  Wl, Wr, Wt, bconv, h, feat, l2b, sel,
                                  U, Vsum, bar0);
  k_vts<<<256, 1024, 0, stream>>>(U, Vsum, mw, sw, SCT, bar1);
  k_route<<<400, 256, 0, stream>>>(Wjm, SCT, gT, delta, accZ0, accZ1,
                                   zbuf, out, bar2);
}

// Round 7
// 580.188 us; speedup vs baseline: 2.4144x; 1.4795x over previous
//
#include <hip/hip_runtime.h>

// ---------------------------------------------------------------------------
// TreeCaps forward, MI355X fp32. 3 persistent kernels.
// Fixed forest: node p's children are 4p+1..4p+4; nodes 0..255 internal.
// R5: fused + monotone RMW-poll barrier -> ~38us/barrier (poll contention +
//     400-on-256 grid imbalance). R6:
//   - k_mega/k_vts: per-graph (8-block) barriers only — all deps are
//     intra-graph; 32 independent counters, graphs decoupled.
//   - k_route: 200 balanced blocks (25 s-pairs x 8 n-chunks, 64KB LDS),
//     flag-broadcast grid barrier (single flag writer, read-only polling),
//     3 pre-zeroed accZ buffers (no in-kernel re-zero).
// ---------------------------------------------------------------------------

#define BG      32
#define NPG     1024
#define NLAY    4
#define INT_PG  256
#define M_INT   8192      // BG*INT_PG
#define NN      32768     // BG*NPG
#define EPG     1023
#define NS      50

// per-subgroup barrier (8 arrivals): monotone counter, low contention.
__device__ __forceinline__ void gbar_sub(unsigned int* cnt, unsigned int target) {
  __syncthreads();
  if (threadIdx.x == 0) {
    __hip_atomic_fetch_add(cnt, 1u, __ATOMIC_ACQ_REL, __HIP_MEMORY_SCOPE_AGENT);
    while (__hip_atomic_load(cnt, __ATOMIC_RELAXED, __HIP_MEMORY_SCOPE_AGENT) < target)
      __builtin_amdgcn_s_sleep(4);
    __builtin_amdgcn_fence(__ATOMIC_ACQUIRE, "agent");
  }
  __syncthreads();
}

// grid barrier, flag-broadcast: arrivals RMW the counter; ONLY the last
// arriver writes `flag`; everyone else read-polls the flag (no RMW storm).
__device__ __forceinline__ void gbar_grid(unsigned int* cnt, unsigned int* flag,
                                          unsigned int phase, unsigned int nblocks) {
  __syncthreads();
  if (threadIdx.x == 0) {
    unsigned int old = __hip_atomic_fetch_add(cnt, 1u, __ATOMIC_ACQ_REL,
                                              __HIP_MEMORY_SCOPE_AGENT);
    if (old == phase * nblocks - 1u) {
      __hip_atomic_store(flag, phase, __ATOMIC_RELEASE, __HIP_MEMORY_SCOPE_AGENT);
    } else {
      while (__hip_atomic_load(flag, __ATOMIC_RELAXED, __HIP_MEMORY_SCOPE_AGENT) < phase)
        __builtin_amdgcn_s_sleep(16);
      __builtin_amdgcn_fence(__ATOMIC_ACQUIRE, "agent");
    }
  }
  __syncthreads();
}

// ======================= mega kernel (256 x 256) ===========================
// block (g = bid>>3, j = bid&7). All barriers per-graph (8 blocks).
__global__ __launch_bounds__(256) void k_mega(
    const int* __restrict__ tids, const int* __restrict__ kids,
    const float* __restrict__ temb, const float* __restrict__ kemb,
    const float* __restrict__ lw, const float* __restrict__ rw,
    const float* __restrict__ Wl, const float* __restrict__ Wr,
    const float* __restrict__ Wt, const float* __restrict__ bconv,
    float* __restrict__ h, float* __restrict__ feat,
    float* __restrict__ l2b,
    float* __restrict__ U, float* __restrict__ Vsum,
    unsigned int* __restrict__ barM) {
  __shared__ union {
    struct { float Ws[32][128]; float AsT[32][36]; } c;                 // 20.6 KB
    struct { unsigned long long keys[1024]; unsigned long long red[256]; } t;
  } sm;
  __shared__ int selS[8];
  int tid = threadIdx.x, bid = blockIdx.x;
  int g = bid >> 3, j = bid & 7;
  unsigned int* bar = barM + g * 64;      // 256B-spaced per-graph counter
  unsigned int bt = 0;

  // ---- phase E: embedding for my 128 nodes; h immutable afterwards ----
  for (int i = tid; i < 4096; i += 256) {
    int n = g * 1024 + j * 128 + (i >> 5), c4 = i & 31;
    float4 v;
    if (c4 < 16) v = *(const float4*)(temb + tids[n] * 64 + c4 * 4);
    else         v = *(const float4*)(kemb + kids[n] * 64 + (c4 - 16) * 4);
    *(float4*)(h + n * 128 + c4 * 4) = v;
  }
  bt += 8; gbar_sub(bar, bt);

  // ---- phase C: 4 conv layers (feat-chained) ----
  int pb = j * 32;
  int tx = tid & 31, ty = tid >> 5;
  int p8 = tid >> 3, c16 = (tid & 7) * 16;
  int rowBase = g * 256 + pb;

  for (int l = 0; l < NLAY; ++l) {
    const float* featPrev = feat + (l - 1) * (M_INT * 128);
    float av[16], bv[16], cv[16];
    {
      int PL = pb + p8;
      const float* hp = (l == 0) ? (h + (g * 1024 + PL) * 128 + c16)
                                 : (featPrev + (g * 256 + PL) * 128 + c16);
      #pragma unroll
      for (int q = 0; q < 4; ++q) {
        float4 t4 = *(const float4*)(hp + q * 4);
        cv[q*4] = t4.x; cv[q*4+1] = t4.y; cv[q*4+2] = t4.z; cv[q*4+3] = t4.w;
      }
      #pragma unroll
      for (int i = 0; i < 16; ++i) { av[i] = 0.f; bv[i] = 0.f; }
      for (int jj = 0; jj < 4; ++jj) {
        int cc = 4 * PL + 1 + jj;
        if (cc < 1024) {
          int e = g * EPG + cc - 1;
          float lv = lw[e], rv = rw[e];
          const float* hc = (l > 0 && cc < 256)
                          ? (featPrev + (g * 256 + cc) * 128 + c16)
                          : (h + (g * 1024 + cc) * 128 + c16);
          #pragma unroll
          for (int q = 0; q < 4; ++q) {
            float4 t4 = *(const float4*)(hc + q * 4);
            av[q*4]   = fmaf(lv, t4.x, av[q*4]);   bv[q*4]   = fmaf(rv, t4.x, bv[q*4]);
            av[q*4+1] = fmaf(lv, t4.y, av[q*4+1]); bv[q*4+1] = fmaf(rv, t4.y, bv[q*4+1]);
            av[q*4+2] = fmaf(lv, t4.z, av[q*4+2]); bv[q*4+2] = fmaf(rv, t4.z, bv[q*4+2]);
            av[q*4+3] = fmaf(lv, t4.w, av[q*4+3]); bv[q*4+3] = fmaf(rv, t4.w, bv[q*4+3]);
          }
        }
      }
    }

    const float* WlL = Wl + l * 16384;
    const float* WrL = Wr + l * 16384;
    const float* WtL = Wt + l * 16384;
    float acc[4][4] = {};
    for (int kc = 0; kc < 12; ++kc) {
      int ssel = kc >> 2;
      const float* wsrc = ((ssel == 0) ? WlL : (ssel == 1) ? WrL : WtL)
                        + ((kc & 3) * 32) * 128;
      float4 wv0, wv1, wv2, wv3;
      {
        int f0 = tid, f1 = tid + 256, f2 = tid + 512, f3 = tid + 768;
        wv0 = *(const float4*)(wsrc + (f0 >> 5) * 128 + (f0 & 31) * 4);
        wv1 = *(const float4*)(wsrc + (f1 >> 5) * 128 + (f1 & 31) * 4);
        wv2 = *(const float4*)(wsrc + (f2 >> 5) * 128 + (f2 & 31) * 4);
        wv3 = *(const float4*)(wsrc + (f3 >> 5) * 128 + (f3 & 31) * 4);
      }
      __syncthreads();
      {
        int f0 = tid, f1 = tid + 256, f2 = tid + 512, f3 = tid + 768;
        *(float4*)&sm.c.Ws[f0 >> 5][(f0 & 31) * 4] = wv0;
        *(float4*)&sm.c.Ws[f1 >> 5][(f1 & 31) * 4] = wv1;
        *(float4*)&sm.c.Ws[f2 >> 5][(f2 & 31) * 4] = wv2;
        *(float4*)&sm.c.Ws[f3 >> 5][(f3 & 31) * 4] = wv3;
      }
      int rel = (tid & 7) - ((kc & 3) << 1);
      if (rel == 0 || rel == 1) {
        int kk0 = rel << 4;
        if (ssel == 0) {
          #pragma unroll
          for (int i = 0; i < 16; ++i) sm.c.AsT[kk0 + i][p8] = av[i];
        } else if (ssel == 1) {
          #pragma unroll
          for (int i = 0; i < 16; ++i) sm.c.AsT[kk0 + i][p8] = bv[i];
        } else {
          #pragma unroll
          for (int i = 0; i < 16; ++i) sm.c.AsT[kk0 + i][p8] = cv[i];
        }
      }
      __syncthreads();
      #pragma unroll
      for (int kk = 0; kk < 32; ++kk) {
        float4 wv = *(float4*)&sm.c.Ws[kk][tx * 4];
        float4 av2 = *(float4*)&sm.c.AsT[kk][ty * 4];
        float aa[4] = {av2.x, av2.y, av2.z, av2.w};
        float ww[4] = {wv.x, wv.y, wv.z, wv.w};
        #pragma unroll
        for (int i = 0; i < 4; ++i)
          #pragma unroll
          for (int jj = 0; jj < 4; ++jj)
            acc[i][jj] = fmaf(aa[i], ww[jj], acc[i][jj]);
      }
    }
    float4 bv4 = *(const float4*)(bconv + l * 128 + tx * 4);
    float bb[4] = {bv4.x, bv4.y, bv4.z, bv4.w};
    float* featL = feat + l * (M_INT * 128);
    #pragma unroll
    for (int i = 0; i < 4; ++i) {
      int r = ty * 4 + i;
      float4 o = make_float4(fmaxf(acc[i][0] + bb[0], 0.f),
                             fmaxf(acc[i][1] + bb[1], 0.f),
                             fmaxf(acc[i][2] + bb[2], 0.f),
                             fmaxf(acc[i][3] + bb[3], 0.f));
      *(float4*)(featL + (rowBase + r) * 128 + tx * 4) = o;
    }
    bt += 8; gbar_sub(bar, bt);
  }

  // ---- phase L2: my 128 nodes of graph g ----
  {
    int lane = tid & 63;
    for (int k = 0; k < 32; ++k) {
      int w = j * 128 + k * 4 + (tid >> 6);         // local node id
      int nd = g * 1024 + w;
      float s = 0.f;
      if (w >= INT_PG) {
        const float* p = h + nd * 128;
        float a = p[lane], b = p[lane + 64];
        s = (a * a + b * b) * 4.f;
      } else {
        int row = (g * INT_PG + w) * 128;
        #pragma unroll
        for (int l = 0; l < 4; ++l) {
          const float* p = feat + l * (M_INT * 128) + row;
          float a = p[lane], b = p[lane + 64];
          s += a * a + b * b;
        }
      }
      #pragma unroll
      for (int off = 32; off; off >>= 1) s += __shfl_down(s, off);
      if (lane == 0) l2b[nd] = s;
    }
  }
  bt += 8; gbar_sub(bar, bt);

  // ---- phase TOPK + BUILDU (j==0 block of each graph) ----
  if (j == 0) {
    for (int i = tid; i < 1024; i += 256) {
      unsigned vb = __float_as_uint(l2b[g * 1024 + i]);
      sm.t.keys[i] = ((unsigned long long)vb << 32) | (unsigned)(~i);
    }
    __syncthreads();
    for (int r = 0; r < 8; ++r) {
      unsigned long long best = 0ULL;
      for (int i = tid; i < 1024; i += 256) {
        unsigned long long k = sm.t.keys[i];
        best = (k > best) ? k : best;
      }
      sm.t.red[tid] = best;
      __syncthreads();
      for (int st = 128; st; st >>= 1) {
        if (tid < st) {
          unsigned long long a = sm.t.red[tid], b = sm.t.red[tid + st];
          sm.t.red[tid] = (b > a) ? b : a;
        }
        __syncthreads();
      }
      if (tid == 0) {
        unsigned long long k = sm.t.red[0];
        int idx = (int)(~(unsigned)(k & 0xffffffffu));
        selS[r] = idx;
        sm.t.keys[idx] = 0ULL;
      }
      __syncthreads();
    }
    for (int i = tid; i < 1024; i += 256) {
      int rank = i >> 7, hh = i & 127;
      int local = selS[rank];
      float4 v;
      if (local >= INT_PG) {
        float x = h[(g * NPG + local) * 128 + hh];
        v = make_float4(x, x, x, x);
      } else {
        int row = (g * INT_PG + local) * 128 + hh;
        v.x = feat[row];
        v.y = feat[M_INT * 128 + row];
        v.z = feat[2 * M_INT * 128 + row];
        v.w = feat[3 * M_INT * 128 + row];
      }
      int o = g * 1024 + rank * 128 + hh;
      ((float4*)U)[o] = v;
      ((float4*)Vsum)[o] = v;
    }
  }
}

// ======================= VTS kernel (256 x 1024) ===========================
// block (g = bid>>3, row/col-block = bid&7). Per-graph barriers only.
__global__ __launch_bounds__(1024) void k_vts(
    const float* __restrict__ U, float* __restrict__ Vsum,
    float* __restrict__ mw, float* __restrict__ sw, float* __restrict__ SCT,
    unsigned int* __restrict__ barV) {
  __shared__ union {
    struct { float4 Vs[1024]; float2 red[1024]; } a;                  // 24 KB
    struct { float4 Us[1024]; float2 ms[1024]; float4 par[1024]; } b; // 40 KB
  } s;
  int g = blockIdx.x >> 3, blk = (blockIdx.x & 7) * 128;
  int tid = threadIdx.x, l = tid & 63, p = tid >> 6;
  unsigned int* bar = barV + g * 64;
  unsigned int bt = 0;

  for (int it = 0; it < 3; ++it) {
    // ---- phase A ----
    s.a.Vs[tid] = ((const float4*)Vsum)[g * 1024 + tid];
    __syncthreads();
    float4 u0 = ((const float4*)U)[g * 1024 + blk + l];
    float4 u1 = ((const float4*)U)[g * 1024 + blk + 64 + l];
    int j0 = p * 64;
    float m0 = -3.4e38f, m1 = -3.4e38f;
    for (int j = j0; j < j0 + 64; ++j) {
      float4 v = s.a.Vs[j];
      float a0 = u0.x * v.x + u0.y * v.y + u0.z * v.z + u0.w * v.w;
      float a1 = u1.x * v.x + u1.y * v.y + u1.z * v.z + u1.w * v.w;
      m0 = fmaxf(m0, a0); m1 = fmaxf(m1, a1);
    }
    s.a.red[tid] = make_float2(m0, m1);
    __syncthreads();
    #pragma unroll
    for (int st = 512; st >= 64; st >>= 1) {
      if (tid < st) {
        float2 a = s.a.red[tid], b = s.a.red[tid + st];
        s.a.red[tid] = make_float2(fmaxf(a.x, b.x), fmaxf(a.y, b.y));
      }
      __syncthreads();
    }
    float2 mm = s.a.red[l];
    __syncthreads();
    float s0 = 0.f, s1 = 0.f;
    for (int j = j0; j < j0 + 64; ++j) {
      float4 v = s.a.Vs[j];
      float a0 = u0.x * v.x + u0.y * v.y + u0.z * v.z + u0.w * v.w;
      float a1 = u1.x * v.x + u1.y * v.y + u1.z * v.z + u1.w * v.w;
      s0 += __expf(a0 - mm.x);
      s1 += __expf(a1 - mm.y);
    }
    s.a.red[tid] = make_float2(s0, s1);
    __syncthreads();
    #pragma unroll
    for (int st = 512; st >= 64; st >>= 1) {
      if (tid < st) {
        float2 a = s.a.red[tid], b = s.a.red[tid + st];
        s.a.red[tid] = make_float2(a.x + b.x, a.y + b.y);
      }
      __syncthreads();
    }
    if (tid < 64) {
      float2 ss = s.a.red[tid];
      mw[g * 1024 + blk + tid] = mm.x;
      mw[g * 1024 + blk + 64 + tid] = mm.y;
      sw[g * 1024 + blk + tid] = ss.x;
      sw[g * 1024 + blk + 64 + tid] = ss.y;
    }
    bt += 8; gbar_sub(bar, bt);

    // ---- phase B ----
    s.b.Us[tid] = ((const float4*)U)[g * 1024 + tid];
    s.b.ms[tid] = make_float2(mw[g * 1024 + tid], 1.0f / sw[g * 1024 + tid]);
    __syncthreads();
    float4 v0 = ((const float4*)Vsum)[g * 1024 + blk + l];
    float4 v1 = ((const float4*)Vsum)[g * 1024 + blk + 64 + l];
    float4 acc0 = make_float4(0.f, 0.f, 0.f, 0.f);
    float4 acc1 = make_float4(0.f, 0.f, 0.f, 0.f);
    int i0 = p * 64;
    for (int i = i0; i < i0 + 64; ++i) {
      float4 uu = s.b.Us[i];
      float2 st2 = s.b.ms[i];
      float a0 = uu.x * v0.x + uu.y * v0.y + uu.z * v0.z + uu.w * v0.w;
      float a1 = uu.x * v1.x + uu.y * v1.y + uu.z * v1.z + uu.w * v1.w;
      float w0 = __expf(a0 - st2.x) * st2.y;
      float w1 = __expf(a1 - st2.x) * st2.y;
      acc0.x = fmaf(w0, uu.x, acc0.x); acc0.y = fmaf(w0, uu.y, acc0.y);
      acc0.z = fmaf(w0, uu.z, acc0.z); acc0.w = fmaf(w0, uu.w, acc0.w);
      acc1.x = fmaf(w1, uu.x, acc1.x); acc1.y = fmaf(w1, uu.y, acc1.y);
      acc1.z = fmaf(w1, uu.z, acc1.z); acc1.w = fmaf(w1, uu.w, acc1.w);
    }
    s.b.par[tid] = acc0;
    __syncthreads();
    #pragma unroll
    for (int st = 512; st >= 64; st >>= 1) {
      if (tid < st) {
        float4 a = s.b.par[tid], b = s.b.par[tid + st];
        s.b.par[tid] = make_float4(a.x + b.x, a.y + b.y, a.z + b.z, a.w + b.w);
      }
      __syncthreads();
    }
    float4 o0 = make_float4(0.f, 0.f, 0.f, 0.f);
    if (tid < 64) o0 = s.b.par[tid];
    __syncthreads();
    s.b.par[tid] = acc1;
    __syncthreads();
    #pragma unroll
    for (int st = 512; st >= 64; st >>= 1) {
      if (tid < st) {
        float4 a = s.b.par[tid], b = s.b.par[tid + st];
        s.b.par[tid] = make_float4(a.x + b.x, a.y + b.y, a.z + b.z, a.w + b.w);
      }
      __syncthreads();
    }
    if (tid < 64) {
      float4 o1 = s.b.par[tid];
      int j0c = blk + tid, j1c = blk + 64 + tid;
      if (it == 2) {
        float sq0 = o0.x * o0.x + o0.y * o0.y + o0.z * o0.z + o0.w * o0.w;
        float f0 = (sq0 / (1.f + sq0)) / (sqrtf(sq0 + 1e-10f) + 1e-8f);
        ((float4*)SCT)[j0c * 32 + g] = make_float4(o0.x * f0, o0.y * f0, o0.z * f0, o0.w * f0);
        float sq1 = o1.x * o1.x + o1.y * o1.y + o1.z * o1.z + o1.w * o1.w;
        float f1 = (sq1 / (1.f + sq1)) / (sqrtf(sq1 + 1e-10f) + 1e-8f);
        ((float4*)SCT)[j1c * 32 + g] = make_float4(o1.x * f1, o1.y * f1, o1.z * f1, o1.w * f1);
      } else {
        float4 w0 = ((const float4*)Vsum)[g * 1024 + j0c];
        float4 w1 = ((const float4*)Vsum)[g * 1024 + j1c];
        ((float4*)Vsum)[g * 1024 + j0c] = make_float4(w0.x + o0.x, w0.y + o0.y,
                                                      w0.z + o0.z, w0.w + o0.w);
        ((float4*)Vsum)[g * 1024 + j1c] = make_float4(w1.x + o1.x, w1.y + o1.y,
                                                      w1.z + o1.z, w1.w + o1.w);
      }
    }
    if (it < 2) { bt += 8; gbar_sub(bar, bt); }
  }
}

// ====================== routing kernel (200 x 256) =========================
// block (sb2 = bid/8 in [0,25): s = {2sb2, 2sb2+1}; nb = bid&7: 128 nodes).
// 64 KB LDS Wjm slice. 9 flag-broadcast grid barriers.
__global__ __launch_bounds__(256) void k_route(
    const float* __restrict__ Wjm,
    const float* __restrict__ SCT, float* __restrict__ gT,
    float* __restrict__ delta,
    float* __restrict__ accA0, float* __restrict__ accA1,
    float* __restrict__ accA2, float* __restrict__ zbuf,
    float* __restrict__ out,
    unsigned int* __restrict__ cnt, unsigned int* __restrict__ flag) {
  __shared__ float4 wl4[4096];     // [s2][nn][c] float4 over m — 64 KB
  int tid = threadIdx.x, bid = blockIdx.x;
  int gtid = bid * 256 + tid;
  unsigned int ph = 0;

  int sb2 = bid >> 3, nb = bid & 7, n0 = nb * 128;
  // load my Wjm slice transposed: wl4[s2*2048 + nn*16 + c] = Wjm[n0+nn][c][2sb2+s2][:]
  for (int i = tid; i < 4096; i += 256) {
    int s2 = i >> 11, nn = (i >> 4) & 127, c = i & 15;
    wl4[i] = *(const float4*)(Wjm + (n0 + nn) * 3200 + (c * 50 + sb2 * 2 + s2) * 4);
  }
  __syncthreads();
  int b = tid & 31, ch = tid >> 5;

  float* accs[3] = { accA0, accA1, accA2 };   // pre-zeroed by host memset
  for (int it = 0; it < 3; ++it) {
    float* accC = accs[it];
    // ---- Z phase: accZ[b][s][c] += sum_n gamma * v ----
    {
      const float4* sct = (const float4*)SCT + n0 * 32 + b;
      float a00 = 0.f, a01 = 0.f, a10 = 0.f, a11 = 0.f;
      for (int nn = 0; nn < 128; ++nn) {
        float4 s4 = sct[nn * 32];
        float gm0, gm1;
        if (it == 0) { gm0 = 0.02f; gm1 = 0.02f; }
        else {
          gm0 = gT[((sb2 * 2 + 0) * 1024 + n0 + nn) * 32 + b];
          gm1 = gT[((sb2 * 2 + 1) * 1024 + n0 + nn) * 32 + b];
        }
        float4 w00 = wl4[nn * 16 + ch],        w01 = wl4[nn * 16 + ch + 8];
        float4 w10 = wl4[2048 + nn * 16 + ch], w11 = wl4[2048 + nn * 16 + ch + 8];
        a00 = fmaf(gm0, w00.x*s4.x + w00.y*s4.y + w00.z*s4.z + w00.w*s4.w, a00);
        a01 = fmaf(gm0, w01.x*s4.x + w01.y*s4.y + w01.z*s4.z + w01.w*s4.w, a01);
        a10 = fmaf(gm1, w10.x*s4.x + w10.y*s4.y + w10.z*s4.z + w10.w*s4.w, a10);
        a11 = fmaf(gm1, w11.x*s4.x + w11.y*s4.y + w11.z*s4.z + w11.w*s4.w, a11);
      }
      int s0 = sb2 * 2;
      atomicAdd(accC + (b * NS + s0) * 16 + ch, a00);
      atomicAdd(accC + (b * NS + s0) * 16 + ch + 8, a01);
      atomicAdd(accC + (b * NS + s0 + 1) * 16 + ch, a10);
      atomicAdd(accC + (b * NS + s0 + 1) * 16 + ch + 8, a11);
    }
    ph += 1; gbar_grid(cnt, flag, ph, 200);
    // ---- squash phase ----
    if (gtid < 1600) {
      const float4* a4 = (const float4*)accC + gtid * 4;
      float4 u0 = a4[0], u1 = a4[1], u2 = a4[2], u3 = a4[3];
      float sq = u0.x*u0.x + u0.y*u0.y + u0.z*u0.z + u0.w*u0.w
               + u1.x*u1.x + u1.y*u1.y + u1.z*u1.z + u1.w*u1.w
               + u2.x*u2.x + u2.y*u2.y + u2.z*u2.z + u2.w*u2.w
               + u3.x*u3.x + u3.y*u3.y + u3.z*u3.z + u3.w*u3.w;
      float f = (sq / (1.f + sq)) / (sqrtf(sq + 1e-10f) + 1e-8f);
      if (it == 2) {
        float lg = sqrtf(sq * f * f + 1e-10f);
        out[gtid] = lg;
        out[gtid + 1600] = lg;
      } else {
        float4* z4 = (float4*)zbuf + gtid * 4;
        z4[0] = make_float4(u0.x * f, u0.y * f, u0.z * f, u0.w * f);
        z4[1] = make_float4(u1.x * f, u1.y * f, u1.z * f, u1.w * f);
        z4[2] = make_float4(u2.x * f, u2.y * f, u2.z * f, u2.w * f);
        z4[3] = make_float4(u3.x * f, u3.y * f, u3.z * f, u3.w * f);
      }
    }
    if (it == 2) break;            // uniform exit
    ph += 1; gbar_grid(cnt, flag, ph, 200);
    // ---- D phase: delta[s][n][b] (+)= sum_c v * z ----
    for (int item = tid; item < 8192; item += 256) {
      int bb = item & 31, nn = (item >> 5) & 127, s2 = item >> 12;
      int s = sb2 * 2 + s2;
      float4 sc4 = ((const float4*)SCT)[(n0 + nn) * 32 + bb];
      const float4* zp = (const float4*)(zbuf + bb * 800 + s * 16);
      float4 z0 = zp[0], z1 = zp[1], z2 = zp[2], z3 = zp[3];
      float zs[16] = {z0.x, z0.y, z0.z, z0.w, z1.x, z1.y, z1.z, z1.w,
                      z2.x, z2.y, z2.z, z2.w, z3.x, z3.y, z3.z, z3.w};
      const float4* wp = wl4 + s2 * 2048 + nn * 16;
      float dd = 0.f;
      #pragma unroll
      for (int c = 0; c < 16; ++c) {
        float4 w = wp[c];
        float y = w.x * sc4.x + w.y * sc4.y + w.z * sc4.z + w.w * sc4.w;
        dd = fmaf(zs[c], y, dd);
      }
      float* dp = delta + (s * 1024 + n0 + nn) * 32 + bb;
      if (it == 0) *dp = dd; else *dp = *dp + dd;
    }
    ph += 1; gbar_grid(cnt, flag, ph, 200);
    // ---- gamma phase: gT = softmax_s(delta), exp cached in gT ----
    if (gtid < 32768) {
      const float* dp = delta + gtid;
      float* gq = gT + gtid;
      float m = -3.4e38f;
      for (int s2 = 0; s2 < NS; ++s2) m = fmaxf(m, dp[s2 * 32768]);
      float sum = 0.f;
      for (int s2 = 0; s2 < NS; ++s2) {
        float e = __expf(dp[s2 * 32768] - m);
        gq[s2 * 32768] = e;
        sum += e;
      }
      float inv = 1.0f / sum;
      for (int s2 = 0; s2 < NS; ++s2) gq[s2 * 32768] *= inv;
    }
    ph += 1; gbar_grid(cnt, flag, ph, 200);
  }
}

// ---------------------------------------------------------------------------
extern "C" void kernel_launch(void* const* d_in, const int* in_sizes, int n_in,
                              void* d_out, int out_size, void* d_ws, size_t ws_size,
                              hipStream_t stream) {
  const int*   type_ids  = (const int*)d_in[0];
  const int*   token_ids = (const int*)d_in[1];
  const float* lw        = (const float*)d_in[4];
  const float* rw        = (const float*)d_in[5];
  const float* temb      = (const float*)d_in[7];
  const float* kemb      = (const float*)d_in[8];
  const float* Wl        = (const float*)d_in[9];
  const float* Wr        = (const float*)d_in[10];
  const float* Wt        = (const float*)d_in[11];
  const float* bconv     = (const float*)d_in[12];
  const float* Wjm       = (const float*)d_in[13];
  float* out = (float*)d_out;
  char* wsb = (char*)d_ws;

  // workspace layout (~36 MB peak; gT/delta overlay h which is dead in route)
  float* h     = (float*)(wsb + 0);          // 16.78 MB (k_mega)
  float* gT    = (float*)(wsb + 0);          // 6.55 MB  (k_route)
  float* delta = (float*)(wsb + 6553600);    // 6.55 MB  (k_route)
  float* feat  = (float*)(wsb + 16777216);   // 16.78 MB (k_mega; dead in route)
  float* l2b   = (float*)(wsb + 33554432);   // 128 KB
  float* U     = (float*)(wsb + 33686528);   // 512 KB
  float* Vsum  = (float*)(wsb + 34210816);   // 512 KB
  float* mw    = (float*)(wsb + 34735104);   // 128 KB
  float* sw    = (float*)(wsb + 34866176);   // 128 KB
  float* SCT   = (float*)(wsb + 34997248);   // 512 KB
  float* accA0 = (float*)(wsb + 35521536);   // 100 KB
  float* accA1 = (float*)(wsb + 35623936);   // 100 KB
  float* accA2 = (float*)(wsb + 35726336);   // 100 KB
  float* zbuf  = (float*)(wsb + 35828736);   // 100 KB
  unsigned int* barM = (unsigned int*)(wsb + 35931136);   // 32 x 256 B
  unsigned int* barV = (unsigned int*)(wsb + 35939328);   // 32 x 256 B
  unsigned int* cntR = (unsigned int*)(wsb + 35947520);
  unsigned int* flgR = (unsigned int*)(wsb + 35947776);

  // zero accA0..2 (+zbuf harmless) and all barrier counters/flags
  hipMemsetAsync(wsb + 35521536, 0, 426496, stream);

  k_mega<<<256, 256, 0, stream>>>(type_ids, token_ids, temb, kemb, lw, rw,
                                  Wl, Wr, Wt, bconv, h, feat, l2b,
                                  U, Vsum, barM);
  k_vts<<<256, 1024, 0, stream>>>(U, Vsum, mw, sw, SCT, barV);
  k_route<<<200, 256, 0, stream>>>(Wjm, SCT, gT, delta, accA0, accA1, accA2,
                                   zbuf, out, cntR, flgR);
}

// Round 8
// 548.163 us; speedup vs baseline: 2.5555x; 1.0584x over previous
//
#include <hip/hip_runtime.h>

// ---------------------------------------------------------------------------
// TreeCaps forward, MI355X fp32. 4 kernels.
// Fixed forest: node p's children are 4p+1..4p+4; nodes 0..255 internal.
// R6: fused mega-kernel at 4 waves/CU starved memory phases (VALUBusy 20%).
// R7: split by parallelism need:
//   k_embed (2048 blk): embedding + fused leaf-l2 (shfl reduce in-register)
//   k_conv  (256 blk): 4 layers, per-graph barriers, pipelined Ws prefetch,
//                      l2 fused into epilogue (shfl + atomicAdd), topk+buildU
//   k_vts   (256 blk x 1024): as R6 (per-graph barriers)
//   k_route (200 blk): as R6 (flag-broadcast grid barrier)
// ---------------------------------------------------------------------------

#define BG      32
#define NPG     1024
#define NLAY    4
#define INT_PG  256
#define M_INT   8192      // BG*INT_PG
#define NN      32768     // BG*NPG
#define EPG     1023
#define NS      50

// per-subgroup barrier (N arrivals): monotone counter, low contention.
__device__ __forceinline__ void gbar_sub(unsigned int* cnt, unsigned int target) {
  __syncthreads();
  if (threadIdx.x == 0) {
    __hip_atomic_fetch_add(cnt, 1u, __ATOMIC_ACQ_REL, __HIP_MEMORY_SCOPE_AGENT);
    while (__hip_atomic_load(cnt, __ATOMIC_RELAXED, __HIP_MEMORY_SCOPE_AGENT) < target)
      __builtin_amdgcn_s_sleep(4);
    __builtin_amdgcn_fence(__ATOMIC_ACQUIRE, "agent");
  }
  __syncthreads();
}

// grid barrier, flag-broadcast: arrivals RMW the counter; ONLY the last
// arriver writes `flag`; everyone else read-polls the flag (no RMW storm).
__device__ __forceinline__ void gbar_grid(unsigned int* cnt, unsigned int* flag,
                                          unsigned int phase, unsigned int nblocks) {
  __syncthreads();
  if (threadIdx.x == 0) {
    unsigned int old = __hip_atomic_fetch_add(cnt, 1u, __ATOMIC_ACQ_REL,
                                              __HIP_MEMORY_SCOPE_AGENT);
    if (old == phase * nblocks - 1u) {
      __hip_atomic_store(flag, phase, __ATOMIC_RELEASE, __HIP_MEMORY_SCOPE_AGENT);
    } else {
      while (__hip_atomic_load(flag, __ATOMIC_RELAXED, __HIP_MEMORY_SCOPE_AGENT) < phase)
        __builtin_amdgcn_s_sleep(16);
      __builtin_amdgcn_fence(__ATOMIC_ACQUIRE, "agent");
    }
  }
  __syncthreads();
}

// ================= embed kernel (2048 x 256): h0 + leaf l2 =================
__global__ __launch_bounds__(256) void k_embed(
    const int* __restrict__ tids, const int* __restrict__ kids,
    const float* __restrict__ temb, const float* __restrict__ kemb,
    float* __restrict__ h, float* __restrict__ l2b) {
  int gtid = blockIdx.x * 256 + threadIdx.x;
  for (int i = gtid; i < NN * 32; i += 524288) {
    int n = i >> 5, c4 = i & 31;
    float4 v;
    if (c4 < 16) v = *(const float4*)(temb + tids[n] * 64 + c4 * 4);
    else         v = *(const float4*)(kemb + kids[n] * 64 + (c4 - 16) * 4);
    *(float4*)(h + n * 128 + c4 * 4) = v;
    // leaf l2 = 4*||h0||^2, reduced across the 32 lanes holding node n
    float s = v.x * v.x + v.y * v.y + v.z * v.z + v.w * v.w;
    s += __shfl_xor(s, 1);  s += __shfl_xor(s, 2);
    s += __shfl_xor(s, 4);  s += __shfl_xor(s, 8);
    s += __shfl_xor(s, 16);
    if (c4 == 0 && (n & 1023) >= INT_PG) l2b[n] = s * 4.f;
  }
}

// ================= conv kernel (256 x 256) =================================
// block (g = bid>>3, j = bid&7): 32 rows of graph g. 4 per-graph barriers.
__global__ __launch_bounds__(256) void k_conv(
    const float* __restrict__ lw, const float* __restrict__ rw,
    const float* __restrict__ Wl, const float* __restrict__ Wr,
    const float* __restrict__ Wt, const float* __restrict__ bconv,
    const float* __restrict__ h, float* __restrict__ feat,
    float* __restrict__ l2b,
    float* __restrict__ U, float* __restrict__ Vsum,
    unsigned int* __restrict__ barC) {
  __shared__ union {
    struct { float Ws[32][128]; float AsT[32][36]; } c;                 // 20.6 KB
    struct { unsigned long long keys[1024]; unsigned long long red[256]; } t;
  } sm;
  __shared__ int selS[8];
  int tid = threadIdx.x, bid = blockIdx.x;
  int g = bid >> 3, j = bid & 7;
  unsigned int* bar = barC + g * 64;
  unsigned int bt = 0;

  int pb = j * 32;
  int tx = tid & 31, ty = tid >> 5;
  int p8 = tid >> 3, c16 = (tid & 7) * 16;
  int rowBase = g * 256 + pb;

  for (int l = 0; l < NLAY; ++l) {
    const float* featPrev = feat + (l - 1) * (M_INT * 128);
    // prologue: gather weighted child sums + own row into registers
    float av[16], bv[16], cv[16];
    {
      int PL = pb + p8;
      const float* hp = (l == 0) ? (h + (g * 1024 + PL) * 128 + c16)
                                 : (featPrev + (g * 256 + PL) * 128 + c16);
      #pragma unroll
      for (int q = 0; q < 4; ++q) {
        float4 t4 = *(const float4*)(hp + q * 4);
        cv[q*4] = t4.x; cv[q*4+1] = t4.y; cv[q*4+2] = t4.z; cv[q*4+3] = t4.w;
      }
      #pragma unroll
      for (int i = 0; i < 16; ++i) { av[i] = 0.f; bv[i] = 0.f; }
      for (int jj = 0; jj < 4; ++jj) {
        int cc = 4 * PL + 1 + jj;
        if (cc < 1024) {
          int e = g * EPG + cc - 1;
          float lv = lw[e], rv = rw[e];
          const float* hc = (l > 0 && cc < 256)
                          ? (featPrev + (g * 256 + cc) * 128 + c16)
                          : (h + (g * 1024 + cc) * 128 + c16);
          #pragma unroll
          for (int q = 0; q < 4; ++q) {
            float4 t4 = *(const float4*)(hc + q * 4);
            av[q*4]   = fmaf(lv, t4.x, av[q*4]);   bv[q*4]   = fmaf(rv, t4.x, bv[q*4]);
            av[q*4+1] = fmaf(lv, t4.y, av[q*4+1]); bv[q*4+1] = fmaf(rv, t4.y, bv[q*4+1]);
            av[q*4+2] = fmaf(lv, t4.z, av[q*4+2]); bv[q*4+2] = fmaf(rv, t4.z, bv[q*4+2]);
            av[q*4+3] = fmaf(lv, t4.w, av[q*4+3]); bv[q*4+3] = fmaf(rv, t4.w, bv[q*4+3]);
          }
        }
      }
    }

    const float* WlL = Wl + l * 16384;
    const float* WrL = Wr + l * 16384;
    const float* WtL = Wt + l * 16384;
    float acc[4][4] = {};
    // software-pipelined weight staging: preload chunk 0
    float4 wv0, wv1, wv2, wv3;
    {
      const float* wsrc = WlL;
      int f0 = tid, f1 = tid + 256, f2 = tid + 512, f3 = tid + 768;
      wv0 = *(const float4*)(wsrc + (f0 >> 5) * 128 + (f0 & 31) * 4);
      wv1 = *(const float4*)(wsrc + (f1 >> 5) * 128 + (f1 & 31) * 4);
      wv2 = *(const float4*)(wsrc + (f2 >> 5) * 128 + (f2 & 31) * 4);
      wv3 = *(const float4*)(wsrc + (f3 >> 5) * 128 + (f3 & 31) * 4);
    }
    for (int kc = 0; kc < 12; ++kc) {
      int ssel = kc >> 2;
      __syncthreads();                        // previous chunk's readers done
      {
        int f0 = tid, f1 = tid + 256, f2 = tid + 512, f3 = tid + 768;
        *(float4*)&sm.c.Ws[f0 >> 5][(f0 & 31) * 4] = wv0;
        *(float4*)&sm.c.Ws[f1 >> 5][(f1 & 31) * 4] = wv1;
        *(float4*)&sm.c.Ws[f2 >> 5][(f2 & 31) * 4] = wv2;
        *(float4*)&sm.c.Ws[f3 >> 5][(f3 & 31) * 4] = wv3;
      }
      int rel = (tid & 7) - ((kc & 3) << 1);
      if (rel == 0 || rel == 1) {
        int kk0 = rel << 4;
        if (ssel == 0) {
          #pragma unroll
          for (int i = 0; i < 16; ++i) sm.c.AsT[kk0 + i][p8] = av[i];
        } else if (ssel == 1) {
          #pragma unroll
          for (int i = 0; i < 16; ++i) sm.c.AsT[kk0 + i][p8] = bv[i];
        } else {
          #pragma unroll
          for (int i = 0; i < 16; ++i) sm.c.AsT[kk0 + i][p8] = cv[i];
        }
      }
      __syncthreads();
      if (kc < 11) {                          // issue next chunk's loads early
        int kc2 = kc + 1, ssel2 = kc2 >> 2;
        const float* wsrc = ((ssel2 == 0) ? WlL : (ssel2 == 1) ? WrL : WtL)
                          + ((kc2 & 3) * 32) * 128;
        int f0 = tid, f1 = tid + 256, f2 = tid + 512, f3 = tid + 768;
        wv0 = *(const float4*)(wsrc + (f0 >> 5) * 128 + (f0 & 31) * 4);
        wv1 = *(const float4*)(wsrc + (f1 >> 5) * 128 + (f1 & 31) * 4);
        wv2 = *(const float4*)(wsrc + (f2 >> 5) * 128 + (f2 & 31) * 4);
        wv3 = *(const float4*)(wsrc + (f3 >> 5) * 128 + (f3 & 31) * 4);
      }
      #pragma unroll
      for (int kk = 0; kk < 32; ++kk) {
        float4 wv = *(float4*)&sm.c.Ws[kk][tx * 4];
        float4 av2 = *(float4*)&sm.c.AsT[kk][ty * 4];
        float aa[4] = {av2.x, av2.y, av2.z, av2.w};
        float ww[4] = {wv.x, wv.y, wv.z, wv.w};
        #pragma unroll
        for (int i = 0; i < 4; ++i)
          #pragma unroll
          for (int jj = 0; jj < 4; ++jj)
            acc[i][jj] = fmaf(aa[i], ww[jj], acc[i][jj]);
      }
    }
    // epilogue: bias+relu, store feat, fused l2 partial (shfl over 32 cols)
    float4 bv4 = *(const float4*)(bconv + l * 128 + tx * 4);
    float bb[4] = {bv4.x, bv4.y, bv4.z, bv4.w};
    float* featL = feat + l * (M_INT * 128);
    float rsum[4];
    #pragma unroll
    for (int i = 0; i < 4; ++i) {
      int r = ty * 4 + i;
      float4 o = make_float4(fmaxf(acc[i][0] + bb[0], 0.f),
                             fmaxf(acc[i][1] + bb[1], 0.f),
                             fmaxf(acc[i][2] + bb[2], 0.f),
                             fmaxf(acc[i][3] + bb[3], 0.f));
      *(float4*)(featL + (rowBase + r) * 128 + tx * 4) = o;
      rsum[i] = o.x * o.x + o.y * o.y + o.z * o.z + o.w * o.w;
    }
    #pragma unroll
    for (int i = 0; i < 4; ++i) {
      rsum[i] += __shfl_xor(rsum[i], 1);  rsum[i] += __shfl_xor(rsum[i], 2);
      rsum[i] += __shfl_xor(rsum[i], 4);  rsum[i] += __shfl_xor(rsum[i], 8);
      rsum[i] += __shfl_xor(rsum[i], 16);
    }
    if (tx == 0) {
      #pragma unroll
      for (int i = 0; i < 4; ++i)
        atomicAdd(l2b + g * 1024 + pb + ty * 4 + i, rsum[i]);
    }
    bt += 8; gbar_sub(bar, bt);   // layer boundary (also orders l2b atomics)
  }

  // ---- TOPK + BUILDU (j==0 block of each graph) ----
  if (j == 0) {
    for (int i = tid; i < 1024; i += 256) {
      unsigned vb = __float_as_uint(l2b[g * 1024 + i]);
      sm.t.keys[i] = ((unsigned long long)vb << 32) | (unsigned)(~i);
    }
    __syncthreads();
    for (int r = 0; r < 8; ++r) {
      unsigned long long best = 0ULL;
      for (int i = tid; i < 1024; i += 256) {
        unsigned long long k = sm.t.keys[i];
        best = (k > best) ? k : best;
      }
      sm.t.red[tid] = best;
      __syncthreads();
      for (int st = 128; st; st >>= 1) {
        if (tid < st) {
          unsigned long long a = sm.t.red[tid], b = sm.t.red[tid + st];
          sm.t.red[tid] = (b > a) ? b : a;
        }
        __syncthreads();
      }
      if (tid == 0) {
        unsigned long long k = sm.t.red[0];
        int idx = (int)(~(unsigned)(k & 0xffffffffu));
        selS[r] = idx;
        sm.t.keys[idx] = 0ULL;
      }
      __syncthreads();
    }
    for (int i = tid; i < 1024; i += 256) {
      int rank = i >> 7, hh = i & 127;
      int local = selS[rank];
      float4 v;
      if (local >= INT_PG) {
        float x = h[(g * NPG + local) * 128 + hh];
        v = make_float4(x, x, x, x);
      } else {
        int row = (g * INT_PG + local) * 128 + hh;
        v.x = feat[row];
        v.y = feat[M_INT * 128 + row];
        v.z = feat[2 * M_INT * 128 + row];
        v.w = feat[3 * M_INT * 128 + row];
      }
      int o = g * 1024 + rank * 128 + hh;
      ((float4*)U)[o] = v;
      ((float4*)Vsum)[o] = v;
    }
  }
}

// ======================= VTS kernel (256 x 1024) ===========================
__global__ __launch_bounds__(1024) void k_vts(
    const float* __restrict__ U, float* __restrict__ Vsum,
    float* __restrict__ mw, float* __restrict__ sw, float* __restrict__ SCT,
    unsigned int* __restrict__ barV) {
  __shared__ union {
    struct { float4 Vs[1024]; float2 red[1024]; } a;                  // 24 KB
    struct { float4 Us[1024]; float2 ms[1024]; float4 par[1024]; } b; // 40 KB
  } s;
  int g = blockIdx.x >> 3, blk = (blockIdx.x & 7) * 128;
  int tid = threadIdx.x, l = tid & 63, p = tid >> 6;
  unsigned int* bar = barV + g * 64;
  unsigned int bt = 0;

  for (int it = 0; it < 3; ++it) {
    // ---- phase A: row softmax stats of alpha = U @ Vsum.T ----
    s.a.Vs[tid] = ((const float4*)Vsum)[g * 1024 + tid];
    __syncthreads();
    float4 u0 = ((const float4*)U)[g * 1024 + blk + l];
    float4 u1 = ((const float4*)U)[g * 1024 + blk + 64 + l];
    int j0 = p * 64;
    float m0 = -3.4e38f, m1 = -3.4e38f;
    for (int j = j0; j < j0 + 64; ++j) {
      float4 v = s.a.Vs[j];
      float a0 = u0.x * v.x + u0.y * v.y + u0.z * v.z + u0.w * v.w;
      float a1 = u1.x * v.x + u1.y * v.y + u1.z * v.z + u1.w * v.w;
      m0 = fmaxf(m0, a0); m1 = fmaxf(m1, a1);
    }
    s.a.red[tid] = make_float2(m0, m1);
    __syncthreads();
    #pragma unroll
    for (int st = 512; st >= 64; st >>= 1) {
      if (tid < st) {
        float2 a = s.a.red[tid], b = s.a.red[tid + st];
        s.a.red[tid] = make_float2(fmaxf(a.x, b.x), fmaxf(a.y, b.y));
      }
      __syncthreads();
    }
    float2 mm = s.a.red[l];
    __syncthreads();
    float s0 = 0.f, s1 = 0.f;
    for (int j = j0; j < j0 + 64; ++j) {
      float4 v = s.a.Vs[j];
      float a0 = u0.x * v.x + u0.y * v.y + u0.z * v.z + u0.w * v.w;
      float a1 = u1.x * v.x + u1.y * v.y + u1.z * v.z + u1.w * v.w;
      s0 += __expf(a0 - mm.x);
      s1 += __expf(a1 - mm.y);
    }
    s.a.red[tid] = make_float2(s0, s1);
    __syncthreads();
    #pragma unroll
    for (int st = 512; st >= 64; st >>= 1) {
      if (tid < st) {
        float2 a = s.a.red[tid], b = s.a.red[tid + st];
        s.a.red[tid] = make_float2(a.x + b.x, a.y + b.y);
      }
      __syncthreads();
    }
    if (tid < 64) {
      float2 ss = s.a.red[tid];
      mw[g * 1024 + blk + tid] = mm.x;
      mw[g * 1024 + blk + 64 + tid] = mm.y;
      sw[g * 1024 + blk + tid] = ss.x;
      sw[g * 1024 + blk + 64 + tid] = ss.y;
    }
    bt += 8; gbar_sub(bar, bt);

    // ---- phase B: Vnew = beta.T @ U ----
    s.b.Us[tid] = ((const float4*)U)[g * 1024 + tid];
    s.b.ms[tid] = make_float2(mw[g * 1024 + tid], 1.0f / sw[g * 1024 + tid]);
    __syncthreads();
    float4 v0 = ((const float4*)Vsum)[g * 1024 + blk + l];
    float4 v1 = ((const float4*)Vsum)[g * 1024 + blk + 64 + l];
    float4 acc0 = make_float4(0.f, 0.f, 0.f, 0.f);
    float4 acc1 = make_float4(0.f, 0.f, 0.f, 0.f);
    int i0 = p * 64;
    for (int i = i0; i < i0 + 64; ++i) {
      float4 uu = s.b.Us[i];
      float2 st2 = s.b.ms[i];
      float a0 = uu.x * v0.x + uu.y * v0.y + uu.z * v0.z + uu.w * v0.w;
      float a1 = uu.x * v1.x + uu.y * v1.y + uu.z * v1.z + uu.w * v1.w;
      float w0 = __expf(a0 - st2.x) * st2.y;
      float w1 = __expf(a1 - st2.x) * st2.y;
      acc0.x = fmaf(w0, uu.x, acc0.x); acc0.y = fmaf(w0, uu.y, acc0.y);
      acc0.z = fmaf(w0, uu.z, acc0.z); acc0.w = fmaf(w0, uu.w, acc0.w);
      acc1.x = fmaf(w1, uu.x, acc1.x); acc1.y = fmaf(w1, uu.y, acc1.y);
      acc1.z = fmaf(w1, uu.z, acc1.z); acc1.w = fmaf(w1, uu.w, acc1.w);
    }
    s.b.par[tid] = acc0;
    __syncthreads();
    #pragma unroll
    for (int st = 512; st >= 64; st >>= 1) {
      if (tid < st) {
        float4 a = s.b.par[tid], b = s.b.par[tid + st];
        s.b.par[tid] = make_float4(a.x + b.x, a.y + b.y, a.z + b.z, a.w + b.w);
      }
      __syncthreads();
    }
    float4 o0 = make_float4(0.f, 0.f, 0.f, 0.f);
    if (tid < 64) o0 = s.b.par[tid];
    __syncthreads();
    s.b.par[tid] = acc1;
    __syncthreads();
    #pragma unroll
    for (int st = 512; st >= 64; st >>= 1) {
      if (tid < st) {
        float4 a = s.b.par[tid], b = s.b.par[tid + st];
        s.b.par[tid] = make_float4(a.x + b.x, a.y + b.y, a.z + b.z, a.w + b.w);
      }
      __syncthreads();
    }
    if (tid < 64) {
      float4 o1 = s.b.par[tid];
      int j0c = blk + tid, j1c = blk + 64 + tid;
      if (it == 2) {
        float sq0 = o0.x * o0.x + o0.y * o0.y + o0.z * o0.z + o0.w * o0.w;
        float f0 = (sq0 / (1.f + sq0)) / (sqrtf(sq0 + 1e-10f) + 1e-8f);
        ((float4*)SCT)[j0c * 32 + g] = make_float4(o0.x * f0, o0.y * f0, o0.z * f0, o0.w * f0);
        float sq1 = o1.x * o1.x + o1.y * o1.y + o1.z * o1.z + o1.w * o1.w;
        float f1 = (sq1 / (1.f + sq1)) / (sqrtf(sq1 + 1e-10f) + 1e-8f);
        ((float4*)SCT)[j1c * 32 + g] = make_float4(o1.x * f1, o1.y * f1, o1.z * f1, o1.w * f1);
      } else {
        float4 w0 = ((const float4*)Vsum)[g * 1024 + j0c];
        float4 w1 = ((const float4*)Vsum)[g * 1024 + j1c];
        ((float4*)Vsum)[g * 1024 + j0c] = make_float4(w0.x + o0.x, w0.y + o0.y,
                                                      w0.z + o0.z, w0.w + o0.w);
        ((float4*)Vsum)[g * 1024 + j1c] = make_float4(w1.x + o1.x, w1.y + o1.y,
                                                      w1.z + o1.z, w1.w + o1.w);
      }
    }
    if (it < 2) { bt += 8; gbar_sub(bar, bt); }
  }
}

// ====================== routing kernel (200 x 256) =========================
__global__ __launch_bounds__(256) void k_route(
    const float* __restrict__ Wjm,
    const float* __restrict__ SCT, float* __restrict__ gT,
    float* __restrict__ delta,
    float* __restrict__ accA0, float* __restrict__ accA1,
    float* __restrict__ accA2, float* __restrict__ zbuf,
    float* __restrict__ out,
    unsigned int* __restrict__ cnt, unsigned int* __restrict__ flag) {
  __shared__ float4 wl4[4096];     // [s2][nn][c] float4 over m — 64 KB
  int tid = threadIdx.x, bid = blockIdx.x;
  int gtid = bid * 256 + tid;
  unsigned int ph = 0;

  int sb2 = bid >> 3, nb = bid & 7, n0 = nb * 128;
  for (int i = tid; i < 4096; i += 256) {
    int s2 = i >> 11, nn = (i >> 4) & 127, c = i & 15;
    wl4[i] = *(const float4*)(Wjm + (n0 + nn) * 3200 + (c * 50 + sb2 * 2 + s2) * 4);
  }
  __syncthreads();
  int b = tid & 31, ch = tid >> 5;

  float* accs[3] = { accA0, accA1, accA2 };   // pre-zeroed by host memset
  for (int it = 0; it < 3; ++it) {
    float* accC = accs[it];
    // ---- Z phase ----
    {
      const float4* sct = (const float4*)SCT + n0 * 32 + b;
      float a00 = 0.f, a01 = 0.f, a10 = 0.f, a11 = 0.f;
      for (int nn = 0; nn < 128; ++nn) {
        float4 s4 = sct[nn * 32];
        float gm0, gm1;
        if (it == 0) { gm0 = 0.02f; gm1 = 0.02f; }
        else {
          gm0 = gT[((sb2 * 2 + 0) * 1024 + n0 + nn) * 32 + b];
          gm1 = gT[((sb2 * 2 + 1) * 1024 + n0 + nn) * 32 + b];
        }
        float4 w00 = wl4[nn * 16 + ch],        w01 = wl4[nn * 16 + ch + 8];
        float4 w10 = wl4[2048 + nn * 16 + ch], w11 = wl4[2048 + nn * 16 + ch + 8];
        a00 = fmaf(gm0, w00.x*s4.x + w00.y*s4.y + w00.z*s4.z + w00.w*s4.w, a00);
        a01 = fmaf(gm0, w01.x*s4.x + w01.y*s4.y + w01.z*s4.z + w01.w*s4.w, a01);
        a10 = fmaf(gm1, w10.x*s4.x + w10.y*s4.y + w10.z*s4.z + w10.w*s4.w, a10);
        a11 = fmaf(gm1, w11.x*s4.x + w11.y*s4.y + w11.z*s4.z + w11.w*s4.w, a11);
      }
      int s0 = sb2 * 2;
      atomicAdd(accC + (b * NS + s0) * 16 + ch, a00);
      atomicAdd(accC + (b * NS + s0) * 16 + ch + 8, a01);
      atomicAdd(accC + (b * NS + s0 + 1) * 16 + ch, a10);
      atomicAdd(accC + (b * NS + s0 + 1) * 16 + ch + 8, a11);
    }
    ph += 1; gbar_grid(cnt, flag, ph, 200);
    // ---- squash phase ----
    if (gtid < 1600) {
      const float4* a4 = (const float4*)accC + gtid * 4;
      float4 u0 = a4[0], u1 = a4[1], u2 = a4[2], u3 = a4[3];
      float sq = u0.x*u0.x + u0.y*u0.y + u0.z*u0.z + u0.w*u0.w
               + u1.x*u1.x + u1.y*u1.y + u1.z*u1.z + u1.w*u1.w
               + u2.x*u2.x + u2.y*u2.y + u2.z*u2.z + u2.w*u2.w
               + u3.x*u3.x + u3.y*u3.y + u3.z*u3.z + u3.w*u3.w;
      float f = (sq / (1.f + sq)) / (sqrtf(sq + 1e-10f) + 1e-8f);
      if (it == 2) {
        float lg = sqrtf(sq * f * f + 1e-10f);
        out[gtid] = lg;
        out[gtid + 1600] = lg;
      } else {
        float4* z4 = (float4*)zbuf + gtid * 4;
        z4[0] = make_float4(u0.x * f, u0.y * f, u0.z * f, u0.w * f);
        z4[1] = make_float4(u1.x * f, u1.y * f, u1.z * f, u1.w * f);
        z4[2] = make_float4(u2.x * f, u2.y * f, u2.z * f, u2.w * f);
        z4[3] = make_float4(u3.x * f, u3.y * f, u3.z * f, u3.w * f);
      }
    }
    if (it == 2) break;            // uniform exit
    ph += 1; gbar_grid(cnt, flag, ph, 200);
    // ---- D phase ----
    for (int item = tid; item < 8192; item += 256) {
      int bb = item & 31, nn = (item >> 5) & 127, s2 = item >> 12;
      int s = sb2 * 2 + s2;
      float4 sc4 = ((const float4*)SCT)[(n0 + nn) * 32 + bb];
      const float4* zp = (const float4*)(zbuf + bb * 800 + s * 16);
      float4 z0 = zp[0], z1 = zp[1], z2 = zp[2], z3 = zp[3];
      float zs[16] = {z0.x, z0.y, z0.z, z0.w, z1.x, z1.y, z1.z, z1.w,
                      z2.x, z2.y, z2.z, z2.w, z3.x, z3.y, z3.z, z3.w};
      const float4* wp = wl4 + s2 * 2048 + nn * 16;
      float dd = 0.f;
      #pragma unroll
      for (int c = 0; c < 16; ++c) {
        float4 w = wp[c];
        float y = w.x * sc4.x + w.y * sc4.y + w.z * sc4.z + w.w * sc4.w;
        dd = fmaf(zs[c], y, dd);
      }
      float* dp = delta + (s * 1024 + n0 + nn) * 32 + bb;
      if (it == 0) *dp = dd; else *dp = *dp + dd;
    }
    ph += 1; gbar_grid(cnt, flag, ph, 200);
    // ---- gamma phase ----
    if (gtid < 32768) {
      const float* dp = delta + gtid;
      float* gq = gT + gtid;
      float m = -3.4e38f;
      for (int s2 = 0; s2 < NS; ++s2) m = fmaxf(m, dp[s2 * 32768]);
      float sum = 0.f;
      for (int s2 = 0; s2 < NS; ++s2) {
        float e = __expf(dp[s2 * 32768] - m);
        gq[s2 * 32768] = e;
        sum += e;
      }
      float inv = 1.0f / sum;
      for (int s2 = 0; s2 < NS; ++s2) gq[s2 * 32768] *= inv;
    }
    ph += 1; gbar_grid(cnt, flag, ph, 200);
  }
}

// ---------------------------------------------------------------------------
extern "C" void kernel_launch(void* const* d_in, const int* in_sizes, int n_in,
                              void* d_out, int out_size, void* d_ws, size_t ws_size,
                              hipStream_t stream) {
  const int*   type_ids  = (const int*)d_in[0];
  const int*   token_ids = (const int*)d_in[1];
  const float* lw        = (const float*)d_in[4];
  const float* rw        = (const float*)d_in[5];
  const float* temb      = (const float*)d_in[7];
  const float* kemb      = (const float*)d_in[8];
  const float* Wl        = (const float*)d_in[9];
  const float* Wr        = (const float*)d_in[10];
  const float* Wt        = (const float*)d_in[11];
  const float* bconv     = (const float*)d_in[12];
  const float* Wjm       = (const float*)d_in[13];
  float* out = (float*)d_out;
  char* wsb = (char*)d_ws;

  // workspace layout (~36 MB peak; gT/delta overlay h which is dead in route)
  float* h     = (float*)(wsb + 0);          // 16.78 MB (embed/conv)
  float* gT    = (float*)(wsb + 0);          // 6.55 MB  (k_route)
  float* delta = (float*)(wsb + 6553600);    // 6.55 MB  (k_route)
  float* feat  = (float*)(wsb + 16777216);   // 16.78 MB (conv; dead in route)
  float* l2b   = (float*)(wsb + 33554432);   // 128 KB
  float* U     = (float*)(wsb + 33686528);   // 512 KB
  float* Vsum  = (float*)(wsb + 34210816);   // 512 KB
  float* mw    = (float*)(wsb + 34735104);   // 128 KB
  float* sw    = (float*)(wsb + 34866176);   // 128 KB
  float* SCT   = (float*)(wsb + 34997248);   // 512 KB
  float* accA0 = (float*)(wsb + 35521536);   // 100 KB
  float* accA1 = (float*)(wsb + 35623936);   // 100 KB
  float* accA2 = (float*)(wsb + 35726336);   // 100 KB
  float* zbuf  = (float*)(wsb + 35828736);   // 100 KB
  unsigned int* barC = (unsigned int*)(wsb + 35931136);   // 32 x 256 B
  unsigned int* barV = (unsigned int*)(wsb + 35939328);   // 32 x 256 B
  unsigned int* cntR = (unsigned int*)(wsb + 35947520);
  unsigned int* flgR = (unsigned int*)(wsb + 35947776);

  // zero accA0..2/zbuf + barriers, and l2b (internal-node atomics)
  hipMemsetAsync(wsb + 35521536, 0, 426496, stream);
  hipMemsetAsync(l2b, 0, 131072, stream);

  k_embed<<<2048, 256, 0, stream>>>(type_ids, token_ids, temb, kemb, h, l2b);
  k_conv<<<256, 256, 0, stream>>>(lw, rw, Wl, Wr, Wt, bconv, h, feat, l2b,
                                  U, Vsum, barC);
  k_vts<<<256, 1024, 0, stream>>>(U, Vsum, mw, sw, SCT, barV);
  k_route<<<200, 256, 0, stream>>>(Wjm, SCT, gT, delta, accA0, accA1, accA2,
                                   zbuf, out, cntR, flgR);
}